// Round 1
// baseline (673.322 us; speedup 1.0000x reference)
//
#include <hip/hip_runtime.h>

#define TOK 2048
#define DIM 1024
#define HID 4096
#define NE 8

typedef unsigned short u16;
typedef __attribute__((ext_vector_type(8))) short s16x8;
typedef __attribute__((ext_vector_type(4))) float f32x4;

__device__ __forceinline__ u16 f2b(float f) {
  unsigned u = __builtin_bit_cast(unsigned, f);
  unsigned r = (u + 0x7fffu + ((u >> 16) & 1u)) >> 16;
  return (u16)r;
}

__device__ __forceinline__ void gld_lds16(const void* g, void* l) {
  __builtin_amdgcn_global_load_lds((const __attribute__((address_space(1))) void*)g,
                                   (__attribute__((address_space(3))) void*)l, 16, 0, 0);
}

// ---------------- gating: one wave per token ----------------
__global__ __launch_bounds__(256) void k_gate(const float* __restrict__ x,
    const float* __restrict__ noise, const float* __restrict__ gw,
    const float* __restrict__ nw, int* __restrict__ tok_e, float* __restrict__ tok_w,
    float* __restrict__ gw_sum, int* __restrict__ counts) {
  const int wid = threadIdx.x >> 6, lane = threadIdx.x & 63;
  const int t = blockIdx.x * 4 + wid;
  const float* xr = x + (size_t)t * DIM + lane * 16;
  float acc[NE];
#pragma unroll
  for (int e = 0; e < NE; ++e) acc[e] = 0.f;
#pragma unroll
  for (int j = 0; j < 4; ++j) {
    float4 xv = *(const float4*)(xr + j * 4);
#pragma unroll
    for (int e = 0; e < NE; ++e) {
      float4 gv = *(const float4*)(gw + e * DIM + lane * 16 + j * 4);
      acc[e] += xv.x * gv.x + xv.y * gv.y + xv.z * gv.z + xv.w * gv.w;
    }
  }
#pragma unroll
  for (int e = 0; e < NE; ++e) {
#pragma unroll
    for (int off = 32; off >= 1; off >>= 1) acc[e] += __shfl_xor(acc[e], off);
  }
  // softmax (for load-balance loss)
  float m = acc[0];
#pragma unroll
  for (int e = 1; e < NE; ++e) m = fmaxf(m, acc[e]);
  float p[NE]; float s = 0.f;
#pragma unroll
  for (int e = 0; e < NE; ++e) { p[e] = expf(acc[e] - m); s += p[e]; }
  float inv = 1.f / s;
  // noisy logits + top-2 (strict > keeps earliest index on ties, like lax.top_k)
  float v[NE];
#pragma unroll
  for (int e = 0; e < NE; ++e) v[e] = acc[e] + noise[t * NE + e] * nw[e];
  float v0 = -3.4e38f, v1 = -3.4e38f; int i0 = 0, i1 = 0;
#pragma unroll
  for (int e = 0; e < NE; ++e) {
    float ve = v[e];
    if (ve > v0) { v1 = v0; i1 = i0; v0 = ve; i0 = e; }
    else if (ve > v1) { v1 = ve; i1 = e; }
  }
  float e1 = expf(v1 - v0);
  float den = 1.f + e1;
  float w0 = 1.f / den, w1 = e1 / den;
  if (lane == 0) {
#pragma unroll
    for (int e = 0; e < NE; ++e) atomicAdd(&gw_sum[e], p[e] * inv);
    tok_e[t * 2] = i0; tok_e[t * 2 + 1] = i1;
    tok_w[t * 2] = w0; tok_w[t * 2 + 1] = w1;
    atomicAdd(&counts[i0], 1);
    atomicAdd(&counts[i1], 1);
  }
}

// ---------------- prefix + load-balance loss ----------------
__global__ void k_prefix_lb(const int* __restrict__ counts, int* __restrict__ prefix,
                            const float* __restrict__ gw_sum, float* __restrict__ loss_out) {
  if (threadIdx.x == 0 && blockIdx.x == 0) {
    int s = 0;
#pragma unroll
    for (int e = 0; e < NE; ++e) { prefix[e] = s; s += counts[e]; }
    float l = 0.f;
#pragma unroll
    for (int e = 0; e < NE; ++e) {
      float d = gw_sum[e] * (1.f / TOK) - 0.125f;
      l += d * d;
    }
    *loss_out = l * (0.01f / NE);
  }
}

// ---------------- build compacted expert lists ----------------
__global__ __launch_bounds__(256) void k_build(const int* __restrict__ tok_e,
    const float* __restrict__ tok_w, const int* __restrict__ prefix,
    int* __restrict__ counts2, int* __restrict__ ent, float* __restrict__ entw) {
  int t = blockIdx.x * 256 + threadIdx.x;
  if (t >= TOK) return;
#pragma unroll
  for (int s = 0; s < 2; ++s) {
    int e = tok_e[t * 2 + s];
    int pos = atomicAdd(&counts2[e], 1);
    int idx = prefix[e] + pos;
    ent[idx] = t * 2 + s;
    entw[idx] = tok_w[t * 2 + s];
  }
}

// ---------------- cast x to bf16 ----------------
__global__ __launch_bounds__(256) void k_cast_x(const float* __restrict__ x, u16* __restrict__ x16) {
  size_t i = ((size_t)blockIdx.x * 256 + threadIdx.x) * 8;
  float4 a = *(const float4*)(x + i);
  float4 b = *(const float4*)(x + i + 4);
  u16 u[8];
  u[0] = f2b(a.x); u[1] = f2b(a.y); u[2] = f2b(a.z); u[3] = f2b(a.w);
  u[4] = f2b(b.x); u[5] = f2b(b.y); u[6] = f2b(b.z); u[7] = f2b(b.w);
  *(s16x8*)(x16 + i) = *(const s16x8*)u;
}

// ---------------- GEMM1: act = (x@w1^T+b1) * silu(x@w2^T+b2)  [gathered rows] ----------------
__global__ __launch_bounds__(256) void k_gemm1(const u16* __restrict__ x16,
    const float* __restrict__ w1, const float* __restrict__ w2,
    const float* __restrict__ b1, const float* __restrict__ b2,
    const int* __restrict__ ent, const int* __restrict__ counts,
    const int* __restrict__ prefix, u16* __restrict__ act) {
  const int e = blockIdx.z, mt = blockIdx.y, nt = blockIdx.x;
  const int cnt = counts[e];
  if (mt * 128 >= cnt) return;
  const int pfx = prefix[e];
  const int tid = threadIdx.x, w = tid >> 6, l = tid & 63;

  __shared__ u16 At[128 * 32];
  __shared__ u16 B1t[128 * 32];
  __shared__ u16 B2t[128 * 32];

  // A staging: wave w stages rows [16w,16w+16) and [64+16w, ...), lane covers 16B
  const int rA0 = 16 * w + (l >> 2);
  const int rA1 = 64 + rA0;
  int g0 = mt * 128 + rA0; if (g0 >= cnt) g0 = cnt - 1;
  int g1 = mt * 128 + rA1; if (g1 >= cnt) g1 = cnt - 1;
  const u16* ga0 = x16 + (size_t)(ent[pfx + g0] >> 1) * DIM + (l & 3) * 8;
  const u16* ga1 = x16 + (size_t)(ent[pfx + g1] >> 1) * DIM + (l & 3) * 8;
  char* ldsA0 = (char*)At + 1024 * w;
  char* ldsA1 = (char*)At + 4096 + 1024 * w;

  // B staging: thread -> (row bn of weight, half bk), fp32->bf16 in regs
  const int bn = tid >> 1;
  const int bk = (tid & 1) * 16;
  const float* pw1 = w1 + ((size_t)e * HID + nt * 128 + bn) * DIM + bk;
  const float* pw2 = w2 + ((size_t)e * HID + nt * 128 + bn) * DIM + bk;
  u16* lb1 = B1t + bn * 32 + bk;
  u16* lb2 = B2t + bn * 32 + bk;

  const int wr = w >> 1, wc = w & 1;
  f32x4 acc1[4][4], acc2[4][4];
#pragma unroll
  for (int m = 0; m < 4; ++m)
#pragma unroll
    for (int n = 0; n < 4; ++n) {
      acc1[m][n] = (f32x4){0.f, 0.f, 0.f, 0.f};
      acc2[m][n] = (f32x4){0.f, 0.f, 0.f, 0.f};
    }

  for (int kt = 0; kt < DIM / 32; ++kt) {
    const int k0 = kt * 32;
    __syncthreads();
    gld_lds16(ga0 + k0, ldsA0);
    gld_lds16(ga1 + k0, ldsA1);
    {
      u16 u1[16], u2[16];
#pragma unroll
      for (int j = 0; j < 4; ++j) {
        float4 f1 = *(const float4*)(pw1 + k0 + j * 4);
        float4 f2 = *(const float4*)(pw2 + k0 + j * 4);
        u1[j * 4 + 0] = f2b(f1.x); u1[j * 4 + 1] = f2b(f1.y);
        u1[j * 4 + 2] = f2b(f1.z); u1[j * 4 + 3] = f2b(f1.w);
        u2[j * 4 + 0] = f2b(f2.x); u2[j * 4 + 1] = f2b(f2.y);
        u2[j * 4 + 2] = f2b(f2.z); u2[j * 4 + 3] = f2b(f2.w);
      }
      *(s16x8*)lb1 = *(const s16x8*)u1;
      *(s16x8*)(lb1 + 8) = *(const s16x8*)(u1 + 8);
      *(s16x8*)lb2 = *(const s16x8*)u2;
      *(s16x8*)(lb2 + 8) = *(const s16x8*)(u2 + 8);
    }
    __syncthreads();
    s16x8 af[4];
#pragma unroll
    for (int m = 0; m < 4; ++m)
      af[m] = *(const s16x8*)(At + (wr * 64 + m * 16 + (l & 15)) * 32 + (l >> 4) * 8);
#pragma unroll
    for (int n = 0; n < 4; ++n) {
      const int br = (wc * 64 + n * 16 + (l & 15)) * 32 + (l >> 4) * 8;
      s16x8 bf1 = *(const s16x8*)(B1t + br);
      s16x8 bf2 = *(const s16x8*)(B2t + br);
#pragma unroll
      for (int m = 0; m < 4; ++m) {
        acc1[m][n] = __builtin_amdgcn_mfma_f32_16x16x32_bf16(af[m], bf1, acc1[m][n], 0, 0, 0);
        acc2[m][n] = __builtin_amdgcn_mfma_f32_16x16x32_bf16(af[m], bf2, acc2[m][n], 0, 0, 0);
      }
    }
  }

  // epilogue: bias + h*silu(g) -> bf16 act
#pragma unroll
  for (int n = 0; n < 4; ++n) {
    const int col = nt * 128 + wc * 64 + n * 16 + (l & 15);
    const float bb1 = b1[(size_t)e * HID + col];
    const float bb2 = b2[(size_t)e * HID + col];
#pragma unroll
    for (int m = 0; m < 4; ++m) {
#pragma unroll
      for (int r = 0; r < 4; ++r) {
        const int row = mt * 128 + wr * 64 + m * 16 + (l >> 4) * 4 + r;
        if (row < cnt) {
          float h = acc1[m][n][r] + bb1;
          float g = acc2[m][n][r] + bb2;
          float a = h * g / (1.f + expf(-g));
          act[(size_t)(pfx + row) * HID + col] = f2b(a);
        }
      }
    }
  }
}

// ---------------- GEMM2: y_slot = w * (act@wp^T + bp) ----------------
__global__ __launch_bounds__(256) void k_gemm2(const u16* __restrict__ act,
    const float* __restrict__ wp, const float* __restrict__ bp,
    const int* __restrict__ ent, const float* __restrict__ entw,
    const int* __restrict__ counts, const int* __restrict__ prefix,
    float* __restrict__ yp) {
  const int e = blockIdx.z, mt = blockIdx.y, nt = blockIdx.x;
  const int cnt = counts[e];
  if (mt * 128 >= cnt) return;
  const int pfx = prefix[e];
  const int tid = threadIdx.x, w = tid >> 6, l = tid & 63;

  __shared__ u16 At[128 * 32];
  __shared__ u16 Bt[128 * 32];

  const int rA0 = 16 * w + (l >> 2);
  const int rA1 = 64 + rA0;
  int g0 = mt * 128 + rA0; if (g0 >= cnt) g0 = cnt - 1;
  int g1 = mt * 128 + rA1; if (g1 >= cnt) g1 = cnt - 1;
  const u16* ga0 = act + (size_t)(pfx + g0) * HID + (l & 3) * 8;
  const u16* ga1 = act + (size_t)(pfx + g1) * HID + (l & 3) * 8;
  char* ldsA0 = (char*)At + 1024 * w;
  char* ldsA1 = (char*)At + 4096 + 1024 * w;

  const int bn = tid >> 1;
  const int bk = (tid & 1) * 16;
  const float* pwp = wp + ((size_t)e * DIM + nt * 128 + bn) * HID + bk;
  u16* lb = Bt + bn * 32 + bk;

  const int wr = w >> 1, wc = w & 1;
  f32x4 acc[4][4];
#pragma unroll
  for (int m = 0; m < 4; ++m)
#pragma unroll
    for (int n = 0; n < 4; ++n) acc[m][n] = (f32x4){0.f, 0.f, 0.f, 0.f};

  for (int kt = 0; kt < HID / 32; ++kt) {
    const int k0 = kt * 32;
    __syncthreads();
    gld_lds16(ga0 + k0, ldsA0);
    gld_lds16(ga1 + k0, ldsA1);
    {
      u16 u[16];
#pragma unroll
      for (int j = 0; j < 4; ++j) {
        float4 f = *(const float4*)(pwp + k0 + j * 4);
        u[j * 4 + 0] = f2b(f.x); u[j * 4 + 1] = f2b(f.y);
        u[j * 4 + 2] = f2b(f.z); u[j * 4 + 3] = f2b(f.w);
      }
      *(s16x8*)lb = *(const s16x8*)u;
      *(s16x8*)(lb + 8) = *(const s16x8*)(u + 8);
    }
    __syncthreads();
    s16x8 af[4];
#pragma unroll
    for (int m = 0; m < 4; ++m)
      af[m] = *(const s16x8*)(At + (wr * 64 + m * 16 + (l & 15)) * 32 + (l >> 4) * 8);
#pragma unroll
    for (int n = 0; n < 4; ++n) {
      const int br = (wc * 64 + n * 16 + (l & 15)) * 32 + (l >> 4) * 8;
      s16x8 bf = *(const s16x8*)(Bt + br);
#pragma unroll
      for (int m = 0; m < 4; ++m)
        acc[m][n] = __builtin_amdgcn_mfma_f32_16x16x32_bf16(af[m], bf, acc[m][n], 0, 0, 0);
    }
  }

#pragma unroll
  for (int n = 0; n < 4; ++n) {
    const int col = nt * 128 + wc * 64 + n * 16 + (l & 15);
    const float bpv = bp[(size_t)e * DIM + col];
#pragma unroll
    for (int m = 0; m < 4; ++m) {
#pragma unroll
      for (int r = 0; r < 4; ++r) {
        const int row = mt * 128 + wr * 64 + m * 16 + (l >> 4) * 4 + r;
        if (row < cnt) {
          const int idx = pfx + row;
          const int en = ent[idx];
          const float wgt = entw[idx];
          yp[(size_t)en * DIM + col] = wgt * (acc[m][n][r] + bpv);
        }
      }
    }
  }
}

// ---------------- final: y = slot0 + slot1 ----------------
__global__ __launch_bounds__(256) void k_final(const float* __restrict__ yp, float* __restrict__ out) {
  size_t i = ((size_t)blockIdx.x * 256 + threadIdx.x) * 4;
  size_t t = i >> 10;
  float4 a = *(const float4*)(yp + i + (t << 10));
  float4 b = *(const float4*)(yp + i + (t << 10) + DIM);
  float4 o;
  o.x = a.x + b.x; o.y = a.y + b.y; o.z = a.z + b.z; o.w = a.w + b.w;
  *(float4*)(out + i) = o;
}

extern "C" void kernel_launch(void* const* d_in, const int* in_sizes, int n_in,
                              void* d_out, int out_size, void* d_ws, size_t ws_size,
                              hipStream_t stream) {
  const float* x      = (const float*)d_in[0];
  const float* noise  = (const float*)d_in[1];
  const float* gate_w = (const float*)d_in[2];
  const float* nw     = (const float*)d_in[3];
  const float* w1     = (const float*)d_in[4];
  const float* b1     = (const float*)d_in[5];
  const float* w2     = (const float*)d_in[6];
  const float* b2     = (const float*)d_in[7];
  const float* wp     = (const float*)d_in[8];
  const float* bp     = (const float*)d_in[9];
  float* out = (float*)d_out;

  char* ws = (char*)d_ws;
  u16* x16    = (u16*)(ws);                       // 4 MB
  u16* act    = (u16*)(ws + ((size_t)4 << 20));   // 32 MB
  float* yp   = (float*)(ws + ((size_t)36 << 20)); // 16 MB
  char* meta  = ws + ((size_t)52 << 20);
  int* tok_e    = (int*)(meta);
  float* tok_w  = (float*)(meta + 16384);
  int* ent      = (int*)(meta + 32768);
  float* entw   = (float*)(meta + 49152);
  int* counts   = (int*)(meta + 65536);
  int* counts2  = (int*)(meta + 65536 + 64);
  int* prefix   = (int*)(meta + 65536 + 128);
  float* gw_sum = (float*)(meta + 65536 + 192);

  hipMemsetAsync(meta + 65536, 0, 256, stream);
  k_gate<<<TOK / 4, 256, 0, stream>>>(x, noise, gate_w, nw, tok_e, tok_w, gw_sum, counts);
  k_prefix_lb<<<1, 64, 0, stream>>>(counts, prefix, gw_sum, out + (size_t)TOK * DIM);
  k_build<<<TOK / 256, 256, 0, stream>>>(tok_e, tok_w, prefix, counts2, ent, entw);
  k_cast_x<<<TOK * DIM / 8 / 256, 256, 0, stream>>>(x, x16);
  k_gemm1<<<dim3(HID / 128, TOK / 128, NE), 256, 0, stream>>>(x16, w1, w2, b1, b2, ent, counts, prefix, act);
  k_gemm2<<<dim3(DIM / 128, TOK / 128, NE), 256, 0, stream>>>(act, wp, bp, ent, entw, counts, prefix, yp);
  k_final<<<TOK * DIM / 4 / 256, 256, 0, stream>>>(yp, out);
}

// Round 2
// 644.874 us; speedup vs baseline: 1.0441x; 1.0441x over previous
//
#include <hip/hip_runtime.h>

#define TOK 2048
#define DIM 1024
#define HID 4096
#define NE 8

typedef unsigned short u16;
typedef __attribute__((ext_vector_type(8))) short s16x8;
typedef __attribute__((ext_vector_type(4))) float f32x4;

__device__ __forceinline__ u16 f2b(float f) {
  unsigned u = __builtin_bit_cast(unsigned, f);
  unsigned r = (u + 0x7fffu + ((u >> 16) & 1u)) >> 16;
  return (u16)r;
}

__device__ __forceinline__ void gld_lds16(const void* g, void* l) {
  __builtin_amdgcn_global_load_lds((const __attribute__((address_space(1))) void*)g,
                                   (__attribute__((address_space(3))) void*)l, 16, 0, 0);
}

// ---------------- gating: one wave per token (also emits x in bf16) ----------------
__global__ __launch_bounds__(256) void k_gate(const float* __restrict__ x,
    const float* __restrict__ noise, const float* __restrict__ gw,
    const float* __restrict__ nw, int* __restrict__ tok_e, float* __restrict__ tok_w,
    float* __restrict__ gw_sum, int* __restrict__ counts, u16* __restrict__ x16) {
  const int wid = threadIdx.x >> 6, lane = threadIdx.x & 63;
  const int t = blockIdx.x * 4 + wid;
  const float* xr = x + (size_t)t * DIM + lane * 16;
  float acc[NE];
#pragma unroll
  for (int e = 0; e < NE; ++e) acc[e] = 0.f;
  u16 xb[16];
#pragma unroll
  for (int j = 0; j < 4; ++j) {
    float4 xv = *(const float4*)(xr + j * 4);
    xb[j * 4 + 0] = f2b(xv.x); xb[j * 4 + 1] = f2b(xv.y);
    xb[j * 4 + 2] = f2b(xv.z); xb[j * 4 + 3] = f2b(xv.w);
#pragma unroll
    for (int e = 0; e < NE; ++e) {
      float4 gv = *(const float4*)(gw + e * DIM + lane * 16 + j * 4);
      acc[e] += xv.x * gv.x + xv.y * gv.y + xv.z * gv.z + xv.w * gv.w;
    }
  }
  *(s16x8*)(x16 + (size_t)t * DIM + lane * 16) = *(const s16x8*)xb;
  *(s16x8*)(x16 + (size_t)t * DIM + lane * 16 + 8) = *(const s16x8*)(xb + 8);
#pragma unroll
  for (int e = 0; e < NE; ++e) {
#pragma unroll
    for (int off = 32; off >= 1; off >>= 1) acc[e] += __shfl_xor(acc[e], off);
  }
  float m = acc[0];
#pragma unroll
  for (int e = 1; e < NE; ++e) m = fmaxf(m, acc[e]);
  float p[NE]; float s = 0.f;
#pragma unroll
  for (int e = 0; e < NE; ++e) { p[e] = expf(acc[e] - m); s += p[e]; }
  float inv = 1.f / s;
  float v[NE];
#pragma unroll
  for (int e = 0; e < NE; ++e) v[e] = acc[e] + noise[t * NE + e] * nw[e];
  float v0 = -3.4e38f, v1 = -3.4e38f; int i0 = 0, i1 = 0;
#pragma unroll
  for (int e = 0; e < NE; ++e) {
    float ve = v[e];
    if (ve > v0) { v1 = v0; i1 = i0; v0 = ve; i0 = e; }
    else if (ve > v1) { v1 = ve; i1 = e; }
  }
  float e1 = expf(v1 - v0);
  float den = 1.f + e1;
  float w0 = 1.f / den, w1 = e1 / den;
  if (lane == 0) {
#pragma unroll
    for (int e = 0; e < NE; ++e) atomicAdd(&gw_sum[e], p[e] * inv);
    tok_e[t * 2] = i0; tok_e[t * 2 + 1] = i1;
    tok_w[t * 2] = w0; tok_w[t * 2 + 1] = w1;
    atomicAdd(&counts[i0], 1);
    atomicAdd(&counts[i1], 1);
  }
}

__global__ void k_prefix_lb(const int* __restrict__ counts, int* __restrict__ prefix,
                            const float* __restrict__ gw_sum, float* __restrict__ loss_out) {
  if (threadIdx.x == 0 && blockIdx.x == 0) {
    int s = 0;
#pragma unroll
    for (int e = 0; e < NE; ++e) { prefix[e] = s; s += counts[e]; }
    float l = 0.f;
#pragma unroll
    for (int e = 0; e < NE; ++e) {
      float d = gw_sum[e] * (1.f / TOK) - 0.125f;
      l += d * d;
    }
    *loss_out = l * (0.01f / NE);
  }
}

__global__ __launch_bounds__(256) void k_build(const int* __restrict__ tok_e,
    const float* __restrict__ tok_w, const int* __restrict__ prefix,
    int* __restrict__ counts2, int* __restrict__ ent, float* __restrict__ entw) {
  int t = blockIdx.x * 256 + threadIdx.x;
  if (t >= TOK) return;
#pragma unroll
  for (int s = 0; s < 2; ++s) {
    int e = tok_e[t * 2 + s];
    int pos = atomicAdd(&counts2[e], 1);
    int idx = prefix[e] + pos;
    ent[idx] = t * 2 + s;
    entw[idx] = tok_w[t * 2 + s];
  }
}

// ---------------- fp32 -> bf16 weight precast ----------------
__global__ __launch_bounds__(256) void k_castw(const float* __restrict__ in, u16* __restrict__ out) {
  size_t i = ((size_t)blockIdx.x * 256 + threadIdx.x) * 8;
  float4 a = *(const float4*)(in + i);
  float4 b = *(const float4*)(in + i + 4);
  u16 u[8];
  u[0] = f2b(a.x); u[1] = f2b(a.y); u[2] = f2b(a.z); u[3] = f2b(a.w);
  u[4] = f2b(b.x); u[5] = f2b(b.y); u[6] = f2b(b.z); u[7] = f2b(b.w);
  *(s16x8*)(out + i) = *(const s16x8*)u;
}

// ================= PATH A: bf16-weight GEMMs, swizzled LDS, 2-phase prefetch =================

// GEMM1: act = (x@w1^T+b1) * silu(x@w2^T+b2)
__global__ __launch_bounds__(256) void k_gemm1f(const u16* __restrict__ x16,
    const u16* __restrict__ w1b, const u16* __restrict__ w2b,
    const float* __restrict__ b1, const float* __restrict__ b2,
    const int* __restrict__ ent, const int* __restrict__ counts,
    const int* __restrict__ prefix, u16* __restrict__ act) {
  const int e = blockIdx.z, mt = blockIdx.y, nt = blockIdx.x;
  const int cnt = counts[e];
  if (mt * 128 >= cnt) return;
  const int pfx = prefix[e];
  const int tid = threadIdx.x, w = tid >> 6, l = tid & 63;

  __shared__ u16 smem[2][3][4096];   // [buf][A,B1,B2][128 rows x 32 bf16]

  // staging: thread covers rows r0 and r0+64, 16B chunk c (source-swizzled)
  const int r0 = tid >> 2;
  const int c = (tid & 3) ^ ((tid >> 3) & 3);
  int g0 = mt * 128 + r0;      if (g0 >= cnt) g0 = cnt - 1;
  int g1 = mt * 128 + r0 + 64; if (g1 >= cnt) g1 = cnt - 1;
  const u16* sa0 = x16 + (size_t)(ent[pfx + g0] >> 1) * DIM + c * 8;
  const u16* sa1 = x16 + (size_t)(ent[pfx + g1] >> 1) * DIM + c * 8;
  const u16* sb10 = w1b + ((size_t)e * HID + nt * 128 + r0) * DIM + c * 8;
  const u16* sb11 = sb10 + (size_t)64 * DIM;
  const u16* sb20 = w2b + ((size_t)e * HID + nt * 128 + r0) * DIM + c * 8;
  const u16* sb21 = sb20 + (size_t)64 * DIM;
  const int o0 = tid * 8, o1 = 2048 + tid * 8;

  const int wr = w >> 1, wc = w & 1;
  const int xs = ((l >> 4) ^ ((l >> 1) & 3)) * 8;     // swizzled read slot
  const int ra = (wr * 64 + (l & 15)) * 32 + xs;
  const int rb = (wc * 64 + (l & 15)) * 32 + xs;

  f32x4 acc1[4][4], acc2[4][4];
#pragma unroll
  for (int m = 0; m < 4; ++m)
#pragma unroll
    for (int n = 0; n < 4; ++n) {
      acc1[m][n] = (f32x4){0.f, 0.f, 0.f, 0.f};
      acc2[m][n] = (f32x4){0.f, 0.f, 0.f, 0.f};
    }

  auto STAGE = [&](int buf, int k0) {
    gld_lds16(sa0 + k0, &smem[buf][0][o0]);
    gld_lds16(sa1 + k0, &smem[buf][0][o1]);
    gld_lds16(sb10 + k0, &smem[buf][1][o0]);
    gld_lds16(sb11 + k0, &smem[buf][1][o1]);
    gld_lds16(sb20 + k0, &smem[buf][2][o0]);
    gld_lds16(sb21 + k0, &smem[buf][2][o1]);
  };

  STAGE(0, 0);
  __syncthreads();
  int cur = 0;
  for (int kt = 0; kt < DIM / 32; ++kt) {
    if (kt < DIM / 32 - 1) STAGE(cur ^ 1, (kt + 1) * 32);
    const u16* A = &smem[cur][0][0];
    const u16* B1 = &smem[cur][1][0];
    const u16* B2 = &smem[cur][2][0];
    s16x8 af[4];
#pragma unroll
    for (int m = 0; m < 4; ++m) af[m] = *(const s16x8*)(A + ra + m * 512);
#pragma unroll
    for (int n = 0; n < 4; ++n) {
      s16x8 bf1 = *(const s16x8*)(B1 + rb + n * 512);
      s16x8 bf2 = *(const s16x8*)(B2 + rb + n * 512);
#pragma unroll
      for (int m = 0; m < 4; ++m) {
        acc1[m][n] = __builtin_amdgcn_mfma_f32_16x16x32_bf16(af[m], bf1, acc1[m][n], 0, 0, 0);
        acc2[m][n] = __builtin_amdgcn_mfma_f32_16x16x32_bf16(af[m], bf2, acc2[m][n], 0, 0, 0);
      }
    }
    __syncthreads();
    cur ^= 1;
  }

#pragma unroll
  for (int n = 0; n < 4; ++n) {
    const int col = nt * 128 + wc * 64 + n * 16 + (l & 15);
    const float bb1 = b1[(size_t)e * HID + col];
    const float bb2 = b2[(size_t)e * HID + col];
#pragma unroll
    for (int m = 0; m < 4; ++m) {
#pragma unroll
      for (int r = 0; r < 4; ++r) {
        const int row = mt * 128 + wr * 64 + m * 16 + (l >> 4) * 4 + r;
        if (row < cnt) {
          float h = acc1[m][n][r] + bb1;
          float g = acc2[m][n][r] + bb2;
          float a = h * g / (1.f + expf(-g));
          act[(size_t)(pfx + row) * HID + col] = f2b(a);
        }
      }
    }
  }
}

// GEMM2: out[token] += w * (act@wp^T + bp)   (atomic combine, 2 slots/token)
__global__ __launch_bounds__(256) void k_gemm2f(const u16* __restrict__ act,
    const u16* __restrict__ wpb, const float* __restrict__ bp,
    const int* __restrict__ ent, const float* __restrict__ entw,
    const int* __restrict__ counts, const int* __restrict__ prefix,
    float* __restrict__ out) {
  const int e = blockIdx.z, mt = blockIdx.y, nt = blockIdx.x;
  const int cnt = counts[e];
  if (mt * 128 >= cnt) return;
  const int pfx = prefix[e];
  const int tid = threadIdx.x, w = tid >> 6, l = tid & 63;

  __shared__ u16 smem[2][2][4096];

  const int r0 = tid >> 2;
  const int c = (tid & 3) ^ ((tid >> 3) & 3);
  int g0 = mt * 128 + r0;      if (g0 >= cnt) g0 = cnt - 1;
  int g1 = mt * 128 + r0 + 64; if (g1 >= cnt) g1 = cnt - 1;
  const u16* sa0 = act + (size_t)(pfx + g0) * HID + c * 8;
  const u16* sa1 = act + (size_t)(pfx + g1) * HID + c * 8;
  const u16* sb0 = wpb + ((size_t)e * DIM + nt * 128 + r0) * HID + c * 8;
  const u16* sb1 = sb0 + (size_t)64 * HID;
  const int o0 = tid * 8, o1 = 2048 + tid * 8;

  const int wr = w >> 1, wc = w & 1;
  const int xs = ((l >> 4) ^ ((l >> 1) & 3)) * 8;
  const int ra = (wr * 64 + (l & 15)) * 32 + xs;
  const int rb = (wc * 64 + (l & 15)) * 32 + xs;

  f32x4 acc[4][4];
#pragma unroll
  for (int m = 0; m < 4; ++m)
#pragma unroll
    for (int n = 0; n < 4; ++n) acc[m][n] = (f32x4){0.f, 0.f, 0.f, 0.f};

  auto STAGE = [&](int buf, int k0) {
    gld_lds16(sa0 + k0, &smem[buf][0][o0]);
    gld_lds16(sa1 + k0, &smem[buf][0][o1]);
    gld_lds16(sb0 + k0, &smem[buf][1][o0]);
    gld_lds16(sb1 + k0, &smem[buf][1][o1]);
  };

  STAGE(0, 0);
  __syncthreads();
  int cur = 0;
  for (int kt = 0; kt < HID / 32; ++kt) {
    if (kt < HID / 32 - 1) STAGE(cur ^ 1, (kt + 1) * 32);
    const u16* A = &smem[cur][0][0];
    const u16* B = &smem[cur][1][0];
    s16x8 af[4];
#pragma unroll
    for (int m = 0; m < 4; ++m) af[m] = *(const s16x8*)(A + ra + m * 512);
#pragma unroll
    for (int n = 0; n < 4; ++n) {
      s16x8 bf = *(const s16x8*)(B + rb + n * 512);
#pragma unroll
      for (int m = 0; m < 4; ++m)
        acc[m][n] = __builtin_amdgcn_mfma_f32_16x16x32_bf16(af[m], bf, acc[m][n], 0, 0, 0);
    }
    __syncthreads();
    cur ^= 1;
  }

#pragma unroll
  for (int n = 0; n < 4; ++n) {
    const int col = nt * 128 + wc * 64 + n * 16 + (l & 15);
    const float bpv = bp[(size_t)e * DIM + col];
#pragma unroll
    for (int m = 0; m < 4; ++m) {
#pragma unroll
      for (int r = 0; r < 4; ++r) {
        const int row = mt * 128 + wr * 64 + m * 16 + (l >> 4) * 4 + r;
        if (row < cnt) {
          const int idx = pfx + row;
          const int en = ent[idx];
          const float wgt = entw[idx];
          atomicAdd(&out[(size_t)(en >> 1) * DIM + col], wgt * (acc[m][n][r] + bpv));
        }
      }
    }
  }
}

// ================= PATH B (fallback, round-1 kernels): fp32 weights, reg-convert =================

__global__ __launch_bounds__(256) void k_gemm1(const u16* __restrict__ x16,
    const float* __restrict__ w1, const float* __restrict__ w2,
    const float* __restrict__ b1, const float* __restrict__ b2,
    const int* __restrict__ ent, const int* __restrict__ counts,
    const int* __restrict__ prefix, u16* __restrict__ act) {
  const int e = blockIdx.z, mt = blockIdx.y, nt = blockIdx.x;
  const int cnt = counts[e];
  if (mt * 128 >= cnt) return;
  const int pfx = prefix[e];
  const int tid = threadIdx.x, w = tid >> 6, l = tid & 63;

  __shared__ u16 At[128 * 32];
  __shared__ u16 B1t[128 * 32];
  __shared__ u16 B2t[128 * 32];

  const int rA0 = 16 * w + (l >> 2);
  const int rA1 = 64 + rA0;
  int g0 = mt * 128 + rA0; if (g0 >= cnt) g0 = cnt - 1;
  int g1 = mt * 128 + rA1; if (g1 >= cnt) g1 = cnt - 1;
  const u16* ga0 = x16 + (size_t)(ent[pfx + g0] >> 1) * DIM + (l & 3) * 8;
  const u16* ga1 = x16 + (size_t)(ent[pfx + g1] >> 1) * DIM + (l & 3) * 8;
  char* ldsA0 = (char*)At + 1024 * w;
  char* ldsA1 = (char*)At + 4096 + 1024 * w;

  const int bn = tid >> 1;
  const int bk = (tid & 1) * 16;
  const float* pw1 = w1 + ((size_t)e * HID + nt * 128 + bn) * DIM + bk;
  const float* pw2 = w2 + ((size_t)e * HID + nt * 128 + bn) * DIM + bk;
  u16* lb1 = B1t + bn * 32 + bk;
  u16* lb2 = B2t + bn * 32 + bk;

  const int wr = w >> 1, wc = w & 1;
  f32x4 acc1[4][4], acc2[4][4];
#pragma unroll
  for (int m = 0; m < 4; ++m)
#pragma unroll
    for (int n = 0; n < 4; ++n) {
      acc1[m][n] = (f32x4){0.f, 0.f, 0.f, 0.f};
      acc2[m][n] = (f32x4){0.f, 0.f, 0.f, 0.f};
    }

  for (int kt = 0; kt < DIM / 32; ++kt) {
    const int k0 = kt * 32;
    __syncthreads();
    gld_lds16(ga0 + k0, ldsA0);
    gld_lds16(ga1 + k0, ldsA1);
    {
      u16 u1[16], u2[16];
#pragma unroll
      for (int j = 0; j < 4; ++j) {
        float4 f1 = *(const float4*)(pw1 + k0 + j * 4);
        float4 f2 = *(const float4*)(pw2 + k0 + j * 4);
        u1[j * 4 + 0] = f2b(f1.x); u1[j * 4 + 1] = f2b(f1.y);
        u1[j * 4 + 2] = f2b(f1.z); u1[j * 4 + 3] = f2b(f1.w);
        u2[j * 4 + 0] = f2b(f2.x); u2[j * 4 + 1] = f2b(f2.y);
        u2[j * 4 + 2] = f2b(f2.z); u2[j * 4 + 3] = f2b(f2.w);
      }
      *(s16x8*)lb1 = *(const s16x8*)u1;
      *(s16x8*)(lb1 + 8) = *(const s16x8*)(u1 + 8);
      *(s16x8*)lb2 = *(const s16x8*)u2;
      *(s16x8*)(lb2 + 8) = *(const s16x8*)(u2 + 8);
    }
    __syncthreads();
    s16x8 af[4];
#pragma unroll
    for (int m = 0; m < 4; ++m)
      af[m] = *(const s16x8*)(At + (wr * 64 + m * 16 + (l & 15)) * 32 + (l >> 4) * 8);
#pragma unroll
    for (int n = 0; n < 4; ++n) {
      const int br = (wc * 64 + n * 16 + (l & 15)) * 32 + (l >> 4) * 8;
      s16x8 bf1 = *(const s16x8*)(B1t + br);
      s16x8 bf2 = *(const s16x8*)(B2t + br);
#pragma unroll
      for (int m = 0; m < 4; ++m) {
        acc1[m][n] = __builtin_amdgcn_mfma_f32_16x16x32_bf16(af[m], bf1, acc1[m][n], 0, 0, 0);
        acc2[m][n] = __builtin_amdgcn_mfma_f32_16x16x32_bf16(af[m], bf2, acc2[m][n], 0, 0, 0);
      }
    }
  }

#pragma unroll
  for (int n = 0; n < 4; ++n) {
    const int col = nt * 128 + wc * 64 + n * 16 + (l & 15);
    const float bb1 = b1[(size_t)e * HID + col];
    const float bb2 = b2[(size_t)e * HID + col];
#pragma unroll
    for (int m = 0; m < 4; ++m) {
#pragma unroll
      for (int r = 0; r < 4; ++r) {
        const int row = mt * 128 + wr * 64 + m * 16 + (l >> 4) * 4 + r;
        if (row < cnt) {
          float h = acc1[m][n][r] + bb1;
          float g = acc2[m][n][r] + bb2;
          float a = h * g / (1.f + expf(-g));
          act[(size_t)(pfx + row) * HID + col] = f2b(a);
        }
      }
    }
  }
}

__global__ __launch_bounds__(256) void k_gemm2(const u16* __restrict__ act,
    const float* __restrict__ wp, const float* __restrict__ bp,
    const int* __restrict__ ent, const float* __restrict__ entw,
    const int* __restrict__ counts, const int* __restrict__ prefix,
    float* __restrict__ yp) {
  const int e = blockIdx.z, mt = blockIdx.y, nt = blockIdx.x;
  const int cnt = counts[e];
  if (mt * 128 >= cnt) return;
  const int pfx = prefix[e];
  const int tid = threadIdx.x, w = tid >> 6, l = tid & 63;

  __shared__ u16 At[128 * 32];
  __shared__ u16 Bt[128 * 32];

  const int rA0 = 16 * w + (l >> 2);
  const int rA1 = 64 + rA0;
  int g0 = mt * 128 + rA0; if (g0 >= cnt) g0 = cnt - 1;
  int g1 = mt * 128 + rA1; if (g1 >= cnt) g1 = cnt - 1;
  const u16* ga0 = act + (size_t)(pfx + g0) * HID + (l & 3) * 8;
  const u16* ga1 = act + (size_t)(pfx + g1) * HID + (l & 3) * 8;
  char* ldsA0 = (char*)At + 1024 * w;
  char* ldsA1 = (char*)At + 4096 + 1024 * w;

  const int bn = tid >> 1;
  const int bk = (tid & 1) * 16;
  const float* pwp = wp + ((size_t)e * DIM + nt * 128 + bn) * HID + bk;
  u16* lb = Bt + bn * 32 + bk;

  const int wr = w >> 1, wc = w & 1;
  f32x4 acc[4][4];
#pragma unroll
  for (int m = 0; m < 4; ++m)
#pragma unroll
    for (int n = 0; n < 4; ++n) acc[m][n] = (f32x4){0.f, 0.f, 0.f, 0.f};

  for (int kt = 0; kt < HID / 32; ++kt) {
    const int k0 = kt * 32;
    __syncthreads();
    gld_lds16(ga0 + k0, ldsA0);
    gld_lds16(ga1 + k0, ldsA1);
    {
      u16 u[16];
#pragma unroll
      for (int j = 0; j < 4; ++j) {
        float4 f = *(const float4*)(pwp + k0 + j * 4);
        u[j * 4 + 0] = f2b(f.x); u[j * 4 + 1] = f2b(f.y);
        u[j * 4 + 2] = f2b(f.z); u[j * 4 + 3] = f2b(f.w);
      }
      *(s16x8*)lb = *(const s16x8*)u;
      *(s16x8*)(lb + 8) = *(const s16x8*)(u + 8);
    }
    __syncthreads();
    s16x8 af[4];
#pragma unroll
    for (int m = 0; m < 4; ++m)
      af[m] = *(const s16x8*)(At + (wr * 64 + m * 16 + (l & 15)) * 32 + (l >> 4) * 8);
#pragma unroll
    for (int n = 0; n < 4; ++n) {
      const int br = (wc * 64 + n * 16 + (l & 15)) * 32 + (l >> 4) * 8;
      s16x8 bf = *(const s16x8*)(Bt + br);
#pragma unroll
      for (int m = 0; m < 4; ++m)
        acc[m][n] = __builtin_amdgcn_mfma_f32_16x16x32_bf16(af[m], bf, acc[m][n], 0, 0, 0);
    }
  }

#pragma unroll
  for (int n = 0; n < 4; ++n) {
    const int col = nt * 128 + wc * 64 + n * 16 + (l & 15);
    const float bpv = bp[(size_t)e * DIM + col];
#pragma unroll
    for (int m = 0; m < 4; ++m) {
#pragma unroll
      for (int r = 0; r < 4; ++r) {
        const int row = mt * 128 + wr * 64 + m * 16 + (l >> 4) * 4 + r;
        if (row < cnt) {
          const int idx = pfx + row;
          const int en = ent[idx];
          const float wgt = entw[idx];
          yp[(size_t)en * DIM + col] = wgt * (acc[m][n][r] + bpv);
        }
      }
    }
  }
}

__global__ __launch_bounds__(256) void k_final(const float* __restrict__ yp, float* __restrict__ out) {
  size_t i = ((size_t)blockIdx.x * 256 + threadIdx.x) * 4;
  size_t t = i >> 10;
  float4 a = *(const float4*)(yp + i + (t << 10));
  float4 b = *(const float4*)(yp + i + (t << 10) + DIM);
  float4 o;
  o.x = a.x + b.x; o.y = a.y + b.y; o.z = a.z + b.z; o.w = a.w + b.w;
  *(float4*)(out + i) = o;
}

extern "C" void kernel_launch(void* const* d_in, const int* in_sizes, int n_in,
                              void* d_out, int out_size, void* d_ws, size_t ws_size,
                              hipStream_t stream) {
  const float* x      = (const float*)d_in[0];
  const float* noise  = (const float*)d_in[1];
  const float* gate_w = (const float*)d_in[2];
  const float* nw     = (const float*)d_in[3];
  const float* w1     = (const float*)d_in[4];
  const float* b1     = (const float*)d_in[5];
  const float* w2     = (const float*)d_in[6];
  const float* b2     = (const float*)d_in[7];
  const float* wp     = (const float*)d_in[8];
  const float* bp     = (const float*)d_in[9];
  float* out = (float*)d_out;
  char* ws = (char*)d_ws;

  const size_t SZ_X16 = (size_t)TOK * DIM * 2;          //  4.2 MB
  const size_t SZ_ACT = (size_t)TOK * 2 * HID * 2;      // 33.6 MB
  const size_t SZ_W   = (size_t)NE * HID * DIM * 2;     // 67.1 MB each
  const size_t NEED_A = SZ_X16 + SZ_ACT + 3 * SZ_W + 65536 + 512;

  if (ws_size >= NEED_A) {
    // ---------- PATH A ----------
    u16* x16 = (u16*)ws;
    u16* act = (u16*)(ws + SZ_X16);
    u16* w1b = (u16*)(ws + SZ_X16 + SZ_ACT);
    u16* w2b = (u16*)(ws + SZ_X16 + SZ_ACT + SZ_W);
    u16* wpb = (u16*)(ws + SZ_X16 + SZ_ACT + 2 * SZ_W);
    char* meta = ws + SZ_X16 + SZ_ACT + 3 * SZ_W;
    int* tok_e    = (int*)(meta);
    float* tok_w  = (float*)(meta + 16384);
    int* ent      = (int*)(meta + 32768);
    float* entw   = (float*)(meta + 49152);
    int* counts   = (int*)(meta + 65536);
    int* counts2  = (int*)(meta + 65536 + 64);
    int* prefix   = (int*)(meta + 65536 + 128);
    float* gw_sum = (float*)(meta + 65536 + 192);

    hipMemsetAsync(meta + 65536, 0, 256, stream);
    hipMemsetAsync(d_out, 0, (size_t)out_size * 4, stream);
    const int nW = (int)((size_t)NE * HID * DIM / 8 / 256);
    k_castw<<<nW, 256, 0, stream>>>(w1, w1b);
    k_castw<<<nW, 256, 0, stream>>>(w2, w2b);
    k_castw<<<nW, 256, 0, stream>>>(wp, wpb);
    k_gate<<<TOK / 4, 256, 0, stream>>>(x, noise, gate_w, nw, tok_e, tok_w, gw_sum, counts, x16);
    k_prefix_lb<<<1, 64, 0, stream>>>(counts, prefix, gw_sum, out + (size_t)TOK * DIM);
    k_build<<<TOK / 256, 256, 0, stream>>>(tok_e, tok_w, prefix, counts2, ent, entw);
    k_gemm1f<<<dim3(HID / 128, TOK / 128, NE), 256, 0, stream>>>(x16, w1b, w2b, b1, b2, ent, counts, prefix, act);
    k_gemm2f<<<dim3(DIM / 128, TOK / 128, NE), 256, 0, stream>>>(act, wpb, bp, ent, entw, counts, prefix, out);
  } else {
    // ---------- PATH B (round-1 fallback) ----------
    u16* x16    = (u16*)(ws);
    u16* act    = (u16*)(ws + ((size_t)4 << 20));
    float* yp   = (float*)(ws + ((size_t)36 << 20));
    char* meta  = ws + ((size_t)52 << 20);
    int* tok_e    = (int*)(meta);
    float* tok_w  = (float*)(meta + 16384);
    int* ent      = (int*)(meta + 32768);
    float* entw   = (float*)(meta + 49152);
    int* counts   = (int*)(meta + 65536);
    int* counts2  = (int*)(meta + 65536 + 64);
    int* prefix   = (int*)(meta + 65536 + 128);
    float* gw_sum = (float*)(meta + 65536 + 192);

    hipMemsetAsync(meta + 65536, 0, 256, stream);
    k_gate<<<TOK / 4, 256, 0, stream>>>(x, noise, gate_w, nw, tok_e, tok_w, gw_sum, counts, x16);
    k_prefix_lb<<<1, 64, 0, stream>>>(counts, prefix, gw_sum, out + (size_t)TOK * DIM);
    k_build<<<TOK / 256, 256, 0, stream>>>(tok_e, tok_w, prefix, counts2, ent, entw);
    k_gemm1<<<dim3(HID / 128, TOK / 128, NE), 256, 0, stream>>>(x16, w1, w2, b1, b2, ent, counts, prefix, act);
    k_gemm2<<<dim3(DIM / 128, TOK / 128, NE), 256, 0, stream>>>(act, wp, bp, ent, entw, counts, prefix, yp);
    k_final<<<TOK * DIM / 4 / 256, 256, 0, stream>>>(yp, out);
  }
}

// Round 3
// 436.633 us; speedup vs baseline: 1.5421x; 1.4769x over previous
//
#include <hip/hip_runtime.h>

#define TOK 2048
#define DIM 1024
#define HID 4096
#define NE 8

typedef unsigned short u16;
typedef __attribute__((ext_vector_type(8))) short s16x8;
typedef __attribute__((ext_vector_type(4))) float f32x4;

__device__ __forceinline__ u16 f2b(float f) {
  unsigned u = __builtin_bit_cast(unsigned, f);
  unsigned r = (u + 0x7fffu + ((u >> 16) & 1u)) >> 16;
  return (u16)r;
}

__device__ __forceinline__ void gld_lds16(const void* g, void* l) {
  __builtin_amdgcn_global_load_lds((const __attribute__((address_space(1))) void*)g,
                                   (__attribute__((address_space(3))) void*)l, 16, 0, 0);
}

// ---------------- gating: one wave per token, atomic-free block reduction ----------------
__global__ __launch_bounds__(256) void k_gate(const float* __restrict__ x,
    const float* __restrict__ noise, const float* __restrict__ gw,
    const float* __restrict__ nw, int* __restrict__ tok_e, float* __restrict__ tok_w,
    int* __restrict__ bhist, float* __restrict__ bgw, u16* __restrict__ x16) {
  const int wid = threadIdx.x >> 6, lane = threadIdx.x & 63;
  const int t = blockIdx.x * 4 + wid;
  const float* xr = x + (size_t)t * DIM + lane * 16;
  float acc[NE];
#pragma unroll
  for (int e = 0; e < NE; ++e) acc[e] = 0.f;
  u16 xb[16];
#pragma unroll
  for (int j = 0; j < 4; ++j) {
    float4 xv = *(const float4*)(xr + j * 4);
    xb[j * 4 + 0] = f2b(xv.x); xb[j * 4 + 1] = f2b(xv.y);
    xb[j * 4 + 2] = f2b(xv.z); xb[j * 4 + 3] = f2b(xv.w);
#pragma unroll
    for (int e = 0; e < NE; ++e) {
      float4 gv = *(const float4*)(gw + e * DIM + lane * 16 + j * 4);
      acc[e] += xv.x * gv.x + xv.y * gv.y + xv.z * gv.z + xv.w * gv.w;
    }
  }
  *(s16x8*)(x16 + (size_t)t * DIM + lane * 16) = *(const s16x8*)xb;
  *(s16x8*)(x16 + (size_t)t * DIM + lane * 16 + 8) = *(const s16x8*)(xb + 8);
#pragma unroll
  for (int e = 0; e < NE; ++e) {
#pragma unroll
    for (int off = 32; off >= 1; off >>= 1) acc[e] += __shfl_xor(acc[e], off);
  }
  // softmax (load-balance loss contribution)
  float m = acc[0];
#pragma unroll
  for (int e = 1; e < NE; ++e) m = fmaxf(m, acc[e]);
  float p[NE]; float s = 0.f;
#pragma unroll
  for (int e = 0; e < NE; ++e) { p[e] = expf(acc[e] - m); s += p[e]; }
  float inv = 1.f / s;
  // noisy logits + top-2 (strict > keeps earliest index on ties)
  float v[NE];
#pragma unroll
  for (int e = 0; e < NE; ++e) v[e] = acc[e] + noise[t * NE + e] * nw[e];
  float v0 = -3.4e38f, v1 = -3.4e38f; int i0 = 0, i1 = 0;
#pragma unroll
  for (int e = 0; e < NE; ++e) {
    float ve = v[e];
    if (ve > v0) { v1 = v0; i1 = i0; v0 = ve; i0 = e; }
    else if (ve > v1) { v1 = ve; i1 = e; }
  }
  float e1 = expf(v1 - v0);
  float den = 1.f + e1;
  float w0 = 1.f / den, w1 = e1 / den;

  __shared__ float pl[4][NE];
  __shared__ int el[4][2];
  if (lane == 0) {
#pragma unroll
    for (int e = 0; e < NE; ++e) pl[wid][e] = p[e] * inv;
    el[wid][0] = i0; el[wid][1] = i1;
    tok_e[t * 2] = i0; tok_e[t * 2 + 1] = i1;
    tok_w[t * 2] = w0; tok_w[t * 2 + 1] = w1;
  }
  __syncthreads();
  if (threadIdx.x < NE) {
    const int e = threadIdx.x;
    float ps = pl[0][e] + pl[1][e] + pl[2][e] + pl[3][e];
    int h = 0;
#pragma unroll
    for (int j = 0; j < 4; ++j) {
      h += (el[j][0] == e);
      h += (el[j][1] == e);
    }
    bgw[blockIdx.x * NE + e] = ps;
    bhist[blockIdx.x * NE + e] = h;
  }
}

// ---------------- scan over 512 gate blocks: offsets, counts, prefix, lb loss ----------------
__global__ __launch_bounds__(512) void k_scan(const int* __restrict__ bhist,
    const float* __restrict__ bgw, int* __restrict__ blk_off, int* __restrict__ prefix,
    int* __restrict__ counts, float* __restrict__ loss_out) {
  const int i = threadIdx.x, lane = i & 63, wv = i >> 6;  // 8 waves x 64
  __shared__ int wsum[8];
  __shared__ float wfs[8];
  __shared__ int etot[8];
  __shared__ float fsum[8];
  for (int e = 0; e < NE; ++e) {
    int v = bhist[i * NE + e];
    int sc = v;
#pragma unroll
    for (int off = 1; off < 64; off <<= 1) {
      int u = __shfl_up(sc, off);
      if (lane >= off) sc += u;
    }
    float f = bgw[i * NE + e];
#pragma unroll
    for (int off = 32; off >= 1; off >>= 1) f += __shfl_xor(f, off);
    if (lane == 63) wsum[wv] = sc;
    if (lane == 0) wfs[wv] = f;
    __syncthreads();
    int base = 0;
    for (int w2 = 0; w2 < wv; ++w2) base += wsum[w2];
    blk_off[i * NE + e] = base + sc - v;
    if (i == 0) {
      float tf = 0.f;
      for (int w2 = 0; w2 < 8; ++w2) tf += wfs[w2];
      fsum[e] = tf;
    }
    if (i == 511) etot[e] = base + sc;
    __syncthreads();
  }
  if (i == 0) {
    int sacc = 0;
    float l = 0.f;
#pragma unroll
    for (int e = 0; e < NE; ++e) { prefix[e] = sacc; counts[e] = etot[e]; sacc += etot[e]; }
#pragma unroll
    for (int e = 0; e < NE; ++e) {
      float d = fsum[e] * (1.f / TOK) - 0.125f;
      l += d * d;
    }
    *loss_out = l * (0.01f / NE);
  }
}

// ---------------- build compacted expert lists (atomic-free, local rank) ----------------
__global__ __launch_bounds__(256) void k_build(const int* __restrict__ tok_e,
    const float* __restrict__ tok_w, const int* __restrict__ prefix,
    const int* __restrict__ blk_off, int* __restrict__ ent, float* __restrict__ entw) {
  const int t = blockIdx.x * 256 + threadIdx.x;
  const int g = t >> 2;
  const int base = (t & 3) * 2;
  int ee[8];
#pragma unroll
  for (int j = 0; j < 8; ++j) ee[j] = tok_e[g * 8 + j];
#pragma unroll
  for (int s = 0; s < 2; ++s) {
    const int e = ee[base + s];
    int rank = 0;
#pragma unroll
    for (int j = 0; j < 8; ++j) rank += (j < base + s) && (ee[j] == e);
    const int idx = prefix[e] + blk_off[g * NE + e] + rank;
    ent[idx] = t * 2 + s;
    entw[idx] = tok_w[t * 2 + s];
  }
}

// ---------------- fused fp32 -> bf16 precast of all three weight tensors ----------------
__global__ __launch_bounds__(256) void k_castw3(const float* __restrict__ w1,
    const float* __restrict__ w2, const float* __restrict__ wp,
    u16* __restrict__ o1, u16* __restrict__ o2, u16* __restrict__ op) {
  const size_t NPT = (size_t)NE * HID * DIM;
  const size_t stride = (size_t)gridDim.x * 256 * 8;
  for (size_t i = ((size_t)blockIdx.x * 256 + threadIdx.x) * 8; i < 3 * NPT; i += stride) {
    const float* in; u16* out; size_t j;
    if (i < NPT)            { in = w1; out = o1; j = i; }
    else if (i < 2 * NPT)   { in = w2; out = o2; j = i - NPT; }
    else                    { in = wp; out = op; j = i - 2 * NPT; }
    float4 a = *(const float4*)(in + j);
    float4 b = *(const float4*)(in + j + 4);
    u16 u[8];
    u[0] = f2b(a.x); u[1] = f2b(a.y); u[2] = f2b(a.z); u[3] = f2b(a.w);
    u[4] = f2b(b.x); u[5] = f2b(b.y); u[6] = f2b(b.z); u[7] = f2b(b.w);
    *(s16x8*)(out + j) = *(const s16x8*)u;
  }
}

// ================= bf16-weight GEMMs, swizzled LDS, 2-phase prefetch =================

// GEMM1: act = (x@w1^T+b1) * silu(x@w2^T+b2)
__global__ __launch_bounds__(256) void k_gemm1f(const u16* __restrict__ x16,
    const u16* __restrict__ w1b, const u16* __restrict__ w2b,
    const float* __restrict__ b1, const float* __restrict__ b2,
    const int* __restrict__ ent, const int* __restrict__ counts,
    const int* __restrict__ prefix, u16* __restrict__ act) {
  const int e = blockIdx.z, mt = blockIdx.y, nt = blockIdx.x;
  const int cnt = counts[e];
  if (mt * 128 >= cnt) return;
  const int pfx = prefix[e];
  const int tid = threadIdx.x, w = tid >> 6, l = tid & 63;

  __shared__ u16 smem[2][3][4096];   // [buf][A,B1,B2][128 rows x 32 bf16]

  const int r0 = tid >> 2;
  const int c = (tid & 3) ^ ((tid >> 3) & 3);
  int g0 = mt * 128 + r0;      if (g0 >= cnt) g0 = cnt - 1;
  int g1 = mt * 128 + r0 + 64; if (g1 >= cnt) g1 = cnt - 1;
  const u16* sa0 = x16 + (size_t)(ent[pfx + g0] >> 1) * DIM + c * 8;
  const u16* sa1 = x16 + (size_t)(ent[pfx + g1] >> 1) * DIM + c * 8;
  const u16* sb10 = w1b + ((size_t)e * HID + nt * 128 + r0) * DIM + c * 8;
  const u16* sb11 = sb10 + (size_t)64 * DIM;
  const u16* sb20 = w2b + ((size_t)e * HID + nt * 128 + r0) * DIM + c * 8;
  const u16* sb21 = sb20 + (size_t)64 * DIM;
  const int o0 = tid * 8, o1 = 2048 + tid * 8;

  const int wr = w >> 1, wc = w & 1;
  const int xs = ((l >> 4) ^ ((l >> 1) & 3)) * 8;     // swizzled read slot
  const int ra = (wr * 64 + (l & 15)) * 32 + xs;
  const int rb = (wc * 64 + (l & 15)) * 32 + xs;

  f32x4 acc1[4][4], acc2[4][4];
#pragma unroll
  for (int m = 0; m < 4; ++m)
#pragma unroll
    for (int n = 0; n < 4; ++n) {
      acc1[m][n] = (f32x4){0.f, 0.f, 0.f, 0.f};
      acc2[m][n] = (f32x4){0.f, 0.f, 0.f, 0.f};
    }

  auto STAGE = [&](int buf, int k0) {
    gld_lds16(sa0 + k0, &smem[buf][0][o0]);
    gld_lds16(sa1 + k0, &smem[buf][0][o1]);
    gld_lds16(sb10 + k0, &smem[buf][1][o0]);
    gld_lds16(sb11 + k0, &smem[buf][1][o1]);
    gld_lds16(sb20 + k0, &smem[buf][2][o0]);
    gld_lds16(sb21 + k0, &smem[buf][2][o1]);
  };

  STAGE(0, 0);
  __syncthreads();
  int cur = 0;
  for (int kt = 0; kt < DIM / 32; ++kt) {
    if (kt < DIM / 32 - 1) STAGE(cur ^ 1, (kt + 1) * 32);
    const u16* A = &smem[cur][0][0];
    const u16* B1 = &smem[cur][1][0];
    const u16* B2 = &smem[cur][2][0];
    s16x8 af[4];
#pragma unroll
    for (int m = 0; m < 4; ++m) af[m] = *(const s16x8*)(A + ra + m * 512);
#pragma unroll
    for (int n = 0; n < 4; ++n) {
      s16x8 bf1 = *(const s16x8*)(B1 + rb + n * 512);
      s16x8 bf2 = *(const s16x8*)(B2 + rb + n * 512);
#pragma unroll
      for (int m = 0; m < 4; ++m) {
        acc1[m][n] = __builtin_amdgcn_mfma_f32_16x16x32_bf16(af[m], bf1, acc1[m][n], 0, 0, 0);
        acc2[m][n] = __builtin_amdgcn_mfma_f32_16x16x32_bf16(af[m], bf2, acc2[m][n], 0, 0, 0);
      }
    }
    __syncthreads();
    cur ^= 1;
  }

#pragma unroll
  for (int n = 0; n < 4; ++n) {
    const int col = nt * 128 + wc * 64 + n * 16 + (l & 15);
    const float bb1 = b1[(size_t)e * HID + col];
    const float bb2 = b2[(size_t)e * HID + col];
#pragma unroll
    for (int m = 0; m < 4; ++m) {
#pragma unroll
      for (int r = 0; r < 4; ++r) {
        const int row = mt * 128 + wr * 64 + m * 16 + (l >> 4) * 4 + r;
        if (row < cnt) {
          float h = acc1[m][n][r] + bb1;
          float g = acc2[m][n][r] + bb2;
          float a = h * g / (1.f + expf(-g));
          act[(size_t)(pfx + row) * HID + col] = f2b(a);
        }
      }
    }
  }
}

// GEMM2: out[token] += w * (act@wp^T + bp)   (atomic combine, exactly 2 adds/element)
__global__ __launch_bounds__(256) void k_gemm2f(const u16* __restrict__ act,
    const u16* __restrict__ wpb, const float* __restrict__ bp,
    const int* __restrict__ ent, const float* __restrict__ entw,
    const int* __restrict__ counts, const int* __restrict__ prefix,
    float* __restrict__ out) {
  const int e = blockIdx.z, mt = blockIdx.y, nt = blockIdx.x;
  const int cnt = counts[e];
  if (mt * 128 >= cnt) return;
  const int pfx = prefix[e];
  const int tid = threadIdx.x, w = tid >> 6, l = tid & 63;

  __shared__ u16 smem[2][2][4096];

  const int r0 = tid >> 2;
  const int c = (tid & 3) ^ ((tid >> 3) & 3);
  int g0 = mt * 128 + r0;      if (g0 >= cnt) g0 = cnt - 1;
  int g1 = mt * 128 + r0 + 64; if (g1 >= cnt) g1 = cnt - 1;
  const u16* sa0 = act + (size_t)(pfx + g0) * HID + c * 8;
  const u16* sa1 = act + (size_t)(pfx + g1) * HID + c * 8;
  const u16* sb0 = wpb + ((size_t)e * DIM + nt * 128 + r0) * HID + c * 8;
  const u16* sb1 = sb0 + (size_t)64 * HID;
  const int o0 = tid * 8, o1 = 2048 + tid * 8;

  const int wr = w >> 1, wc = w & 1;
  const int xs = ((l >> 4) ^ ((l >> 1) & 3)) * 8;
  const int ra = (wr * 64 + (l & 15)) * 32 + xs;
  const int rb = (wc * 64 + (l & 15)) * 32 + xs;

  f32x4 acc[4][4];
#pragma unroll
  for (int m = 0; m < 4; ++m)
#pragma unroll
    for (int n = 0; n < 4; ++n) acc[m][n] = (f32x4){0.f, 0.f, 0.f, 0.f};

  auto STAGE = [&](int buf, int k0) {
    gld_lds16(sa0 + k0, &smem[buf][0][o0]);
    gld_lds16(sa1 + k0, &smem[buf][0][o1]);
    gld_lds16(sb0 + k0, &smem[buf][1][o0]);
    gld_lds16(sb1 + k0, &smem[buf][1][o1]);
  };

  STAGE(0, 0);
  __syncthreads();
  int cur = 0;
  for (int kt = 0; kt < HID / 32; ++kt) {
    if (kt < HID / 32 - 1) STAGE(cur ^ 1, (kt + 1) * 32);
    const u16* A = &smem[cur][0][0];
    const u16* B = &smem[cur][1][0];
    s16x8 af[4];
#pragma unroll
    for (int m = 0; m < 4; ++m) af[m] = *(const s16x8*)(A + ra + m * 512);
#pragma unroll
    for (int n = 0; n < 4; ++n) {
      s16x8 bf = *(const s16x8*)(B + rb + n * 512);
#pragma unroll
      for (int m = 0; m < 4; ++m)
        acc[m][n] = __builtin_amdgcn_mfma_f32_16x16x32_bf16(af[m], bf, acc[m][n], 0, 0, 0);
    }
    __syncthreads();
    cur ^= 1;
  }

#pragma unroll
  for (int n = 0; n < 4; ++n) {
    const int col = nt * 128 + wc * 64 + n * 16 + (l & 15);
    const float bpv = bp[(size_t)e * DIM + col];
#pragma unroll
    for (int m = 0; m < 4; ++m) {
#pragma unroll
      for (int r = 0; r < 4; ++r) {
        const int row = mt * 128 + wr * 64 + m * 16 + (l >> 4) * 4 + r;
        if (row < cnt) {
          const int idx = pfx + row;
          const int en = ent[idx];
          const float wgt = entw[idx];
          atomicAdd(&out[(size_t)(en >> 1) * DIM + col], wgt * (acc[m][n][r] + bpv));
        }
      }
    }
  }
}

extern "C" void kernel_launch(void* const* d_in, const int* in_sizes, int n_in,
                              void* d_out, int out_size, void* d_ws, size_t ws_size,
                              hipStream_t stream) {
  const float* x      = (const float*)d_in[0];
  const float* noise  = (const float*)d_in[1];
  const float* gate_w = (const float*)d_in[2];
  const float* nw     = (const float*)d_in[3];
  const float* w1     = (const float*)d_in[4];
  const float* b1     = (const float*)d_in[5];
  const float* w2     = (const float*)d_in[6];
  const float* b2     = (const float*)d_in[7];
  const float* wp     = (const float*)d_in[8];
  const float* bp     = (const float*)d_in[9];
  float* out = (float*)d_out;
  char* ws = (char*)d_ws;

  const size_t SZ_X16 = (size_t)TOK * DIM * 2;
  const size_t SZ_ACT = (size_t)TOK * 2 * HID * 2;
  const size_t SZ_W   = (size_t)NE * HID * DIM * 2;

  u16* x16 = (u16*)ws;
  u16* act = (u16*)(ws + SZ_X16);
  u16* w1b = (u16*)(ws + SZ_X16 + SZ_ACT);
  u16* w2b = (u16*)(ws + SZ_X16 + SZ_ACT + SZ_W);
  u16* wpb = (u16*)(ws + SZ_X16 + SZ_ACT + 2 * SZ_W);
  char* meta = ws + SZ_X16 + SZ_ACT + 3 * SZ_W;
  int*   tok_e   = (int*)(meta);
  float* tok_w   = (float*)(meta + 16384);
  int*   ent     = (int*)(meta + 32768);
  float* entw    = (float*)(meta + 49152);
  int*   bhist   = (int*)(meta + 65536);
  float* bgw     = (float*)(meta + 65536 + 16384);
  int*   blk_off = (int*)(meta + 65536 + 32768);
  int*   counts  = (int*)(meta + 65536 + 49152);
  int*   prefix  = (int*)(meta + 65536 + 49152 + 256);

  hipMemsetAsync(d_out, 0, (size_t)out_size * 4, stream);
  k_gate<<<TOK / 4, 256, 0, stream>>>(x, noise, gate_w, nw, tok_e, tok_w, bhist, bgw, x16);
  k_scan<<<1, 512, 0, stream>>>(bhist, bgw, blk_off, prefix, counts, out + (size_t)TOK * DIM);
  k_build<<<TOK / 256, 256, 0, stream>>>(tok_e, tok_w, prefix, blk_off, ent, entw);
  k_castw3<<<2048, 256, 0, stream>>>(w1, w2, wp, w1b, w2b, wpb);
  k_gemm1f<<<dim3(HID / 128, TOK / 128, NE), 256, 0, stream>>>(x16, w1b, w2b, b1, b2, ent, counts, prefix, act);
  k_gemm2f<<<dim3(DIM / 128, TOK / 128, NE), 256, 0, stream>>>(act, wpb, bp, ent, entw, counts, prefix, out);
}

// Round 4
// 411.233 us; speedup vs baseline: 1.6373x; 1.0618x over previous
//
#include <hip/hip_runtime.h>

#define TOK 2048
#define DIM 1024
#define HID 4096
#define NE 8
#define KSPLIT 4

typedef unsigned short u16;
typedef __attribute__((ext_vector_type(8))) short s16x8;
typedef __attribute__((ext_vector_type(4))) float f32x4;

__device__ __forceinline__ u16 f2b(float f) {
  unsigned u = __builtin_bit_cast(unsigned, f);
  unsigned r = (u + 0x7fffu + ((u >> 16) & 1u)) >> 16;
  return (u16)r;
}

__device__ __forceinline__ void gld_lds16(const void* g, void* l) {
  __builtin_amdgcn_global_load_lds((const __attribute__((address_space(1))) void*)g,
                                   (__attribute__((address_space(3))) void*)l, 16, 0, 0);
}

// ---------------- gating: one wave per token, atomic-free block reduction ----------------
__global__ __launch_bounds__(256) void k_gate(const float* __restrict__ x,
    const float* __restrict__ noise, const float* __restrict__ gw,
    const float* __restrict__ nw, int* __restrict__ tok_e, float* __restrict__ tok_w,
    int* __restrict__ bhist, float* __restrict__ bgw, u16* __restrict__ x16) {
  const int wid = threadIdx.x >> 6, lane = threadIdx.x & 63;
  const int t = blockIdx.x * 4 + wid;
  const float* xr = x + (size_t)t * DIM + lane * 16;
  float acc[NE];
#pragma unroll
  for (int e = 0; e < NE; ++e) acc[e] = 0.f;
  u16 xb[16];
#pragma unroll
  for (int j = 0; j < 4; ++j) {
    float4 xv = *(const float4*)(xr + j * 4);
    xb[j * 4 + 0] = f2b(xv.x); xb[j * 4 + 1] = f2b(xv.y);
    xb[j * 4 + 2] = f2b(xv.z); xb[j * 4 + 3] = f2b(xv.w);
#pragma unroll
    for (int e = 0; e < NE; ++e) {
      float4 gv = *(const float4*)(gw + e * DIM + lane * 16 + j * 4);
      acc[e] += xv.x * gv.x + xv.y * gv.y + xv.z * gv.z + xv.w * gv.w;
    }
  }
  *(s16x8*)(x16 + (size_t)t * DIM + lane * 16) = *(const s16x8*)xb;
  *(s16x8*)(x16 + (size_t)t * DIM + lane * 16 + 8) = *(const s16x8*)(xb + 8);
#pragma unroll
  for (int e = 0; e < NE; ++e) {
#pragma unroll
    for (int off = 32; off >= 1; off >>= 1) acc[e] += __shfl_xor(acc[e], off);
  }
  float m = acc[0];
#pragma unroll
  for (int e = 1; e < NE; ++e) m = fmaxf(m, acc[e]);
  float p[NE]; float s = 0.f;
#pragma unroll
  for (int e = 0; e < NE; ++e) { p[e] = expf(acc[e] - m); s += p[e]; }
  float inv = 1.f / s;
  float v[NE];
#pragma unroll
  for (int e = 0; e < NE; ++e) v[e] = acc[e] + noise[t * NE + e] * nw[e];
  float v0 = -3.4e38f, v1 = -3.4e38f; int i0 = 0, i1 = 0;
#pragma unroll
  for (int e = 0; e < NE; ++e) {
    float ve = v[e];
    if (ve > v0) { v1 = v0; i1 = i0; v0 = ve; i0 = e; }
    else if (ve > v1) { v1 = ve; i1 = e; }
  }
  float e1 = expf(v1 - v0);
  float den = 1.f + e1;
  float w0 = 1.f / den, w1 = e1 / den;

  __shared__ float pl[4][NE];
  __shared__ int el[4][2];
  if (lane == 0) {
#pragma unroll
    for (int e = 0; e < NE; ++e) pl[wid][e] = p[e] * inv;
    el[wid][0] = i0; el[wid][1] = i1;
    tok_e[t * 2] = i0; tok_e[t * 2 + 1] = i1;
    tok_w[t * 2] = w0; tok_w[t * 2 + 1] = w1;
  }
  __syncthreads();
  if (threadIdx.x < NE) {
    const int e = threadIdx.x;
    float ps = pl[0][e] + pl[1][e] + pl[2][e] + pl[3][e];
    int h = 0;
#pragma unroll
    for (int j = 0; j < 4; ++j) {
      h += (el[j][0] == e);
      h += (el[j][1] == e);
    }
    bgw[blockIdx.x * NE + e] = ps;
    bhist[blockIdx.x * NE + e] = h;
  }
}

// ---------------- scan over 512 gate blocks ----------------
__global__ __launch_bounds__(512) void k_scan(const int* __restrict__ bhist,
    const float* __restrict__ bgw, int* __restrict__ blk_off, int* __restrict__ prefix,
    int* __restrict__ counts, float* __restrict__ loss_out) {
  const int i = threadIdx.x, lane = i & 63, wv = i >> 6;
  __shared__ int wsum[8];
  __shared__ float wfs[8];
  __shared__ int etot[8];
  __shared__ float fsum[8];
  for (int e = 0; e < NE; ++e) {
    int v = bhist[i * NE + e];
    int sc = v;
#pragma unroll
    for (int off = 1; off < 64; off <<= 1) {
      int u = __shfl_up(sc, off);
      if (lane >= off) sc += u;
    }
    float f = bgw[i * NE + e];
#pragma unroll
    for (int off = 32; off >= 1; off >>= 1) f += __shfl_xor(f, off);
    if (lane == 63) wsum[wv] = sc;
    if (lane == 0) wfs[wv] = f;
    __syncthreads();
    int base = 0;
    for (int w2 = 0; w2 < wv; ++w2) base += wsum[w2];
    blk_off[i * NE + e] = base + sc - v;
    if (i == 0) {
      float tf = 0.f;
      for (int w2 = 0; w2 < 8; ++w2) tf += wfs[w2];
      fsum[e] = tf;
    }
    if (i == 511) etot[e] = base + sc;
    __syncthreads();
  }
  if (i == 0) {
    int sacc = 0;
    float l = 0.f;
#pragma unroll
    for (int e = 0; e < NE; ++e) { prefix[e] = sacc; counts[e] = etot[e]; sacc += etot[e]; }
#pragma unroll
    for (int e = 0; e < NE; ++e) {
      float d = fsum[e] * (1.f / TOK) - 0.125f;
      l += d * d;
    }
    *loss_out = l * (0.01f / NE);
  }
}

// ---------------- build compacted expert lists ----------------
__global__ __launch_bounds__(256) void k_build(const int* __restrict__ tok_e,
    const float* __restrict__ tok_w, const int* __restrict__ prefix,
    const int* __restrict__ blk_off, int* __restrict__ ent, float* __restrict__ entw) {
  const int t = blockIdx.x * 256 + threadIdx.x;
  const int g = t >> 2;
  const int base = (t & 3) * 2;
  int ee[8];
#pragma unroll
  for (int j = 0; j < 8; ++j) ee[j] = tok_e[g * 8 + j];
#pragma unroll
  for (int s = 0; s < 2; ++s) {
    const int e = ee[base + s];
    int rank = 0;
#pragma unroll
    for (int j = 0; j < 8; ++j) rank += (j < base + s) && (ee[j] == e);
    const int idx = prefix[e] + blk_off[g * NE + e] + rank;
    ent[idx] = t * 2 + s;
    entw[idx] = tok_w[t * 2 + s];
  }
}

// ---------------- fused fp32 -> bf16 precast ----------------
__global__ __launch_bounds__(256) void k_castw3(const float* __restrict__ w1,
    const float* __restrict__ w2, const float* __restrict__ wp,
    u16* __restrict__ o1, u16* __restrict__ o2, u16* __restrict__ op) {
  const size_t NPT = (size_t)NE * HID * DIM;
  const size_t stride = (size_t)gridDim.x * 256 * 8;
  for (size_t i = ((size_t)blockIdx.x * 256 + threadIdx.x) * 8; i < 3 * NPT; i += stride) {
    const float* in; u16* out; size_t j;
    if (i < NPT)            { in = w1; out = o1; j = i; }
    else if (i < 2 * NPT)   { in = w2; out = o2; j = i - NPT; }
    else                    { in = wp; out = op; j = i - 2 * NPT; }
    float4 a = *(const float4*)(in + j);
    float4 b = *(const float4*)(in + j + 4);
    u16 u[8];
    u[0] = f2b(a.x); u[1] = f2b(a.y); u[2] = f2b(a.z); u[3] = f2b(a.w);
    u[4] = f2b(b.x); u[5] = f2b(b.y); u[6] = f2b(b.z); u[7] = f2b(b.w);
    *(s16x8*)(out + j) = *(const s16x8*)u;
  }
}

// ================= bf16-weight GEMMs =================

// GEMM1: act = (x@w1^T+b1) * silu(x@w2^T+b2)
__global__ __launch_bounds__(256) void k_gemm1f(const u16* __restrict__ x16,
    const u16* __restrict__ w1b, const u16* __restrict__ w2b,
    const float* __restrict__ b1, const float* __restrict__ b2,
    const int* __restrict__ ent, const int* __restrict__ counts,
    const int* __restrict__ prefix, u16* __restrict__ act) {
  const int e = blockIdx.z, mt = blockIdx.y, nt = blockIdx.x;
  const int cnt = counts[e];
  if (mt * 128 >= cnt) return;
  const int pfx = prefix[e];
  const int tid = threadIdx.x, w = tid >> 6, l = tid & 63;

  __shared__ u16 smem[2][3][4096];

  const int r0 = tid >> 2;
  const int c = (tid & 3) ^ ((tid >> 3) & 3);
  int g0 = mt * 128 + r0;      if (g0 >= cnt) g0 = cnt - 1;
  int g1 = mt * 128 + r0 + 64; if (g1 >= cnt) g1 = cnt - 1;
  const u16* sa0 = x16 + (size_t)(ent[pfx + g0] >> 1) * DIM + c * 8;
  const u16* sa1 = x16 + (size_t)(ent[pfx + g1] >> 1) * DIM + c * 8;
  const u16* sb10 = w1b + ((size_t)e * HID + nt * 128 + r0) * DIM + c * 8;
  const u16* sb11 = sb10 + (size_t)64 * DIM;
  const u16* sb20 = w2b + ((size_t)e * HID + nt * 128 + r0) * DIM + c * 8;
  const u16* sb21 = sb20 + (size_t)64 * DIM;
  const int o0 = tid * 8, o1 = 2048 + tid * 8;

  const int wr = w >> 1, wc = w & 1;
  const int xs = ((l >> 4) ^ ((l >> 1) & 3)) * 8;
  const int ra = (wr * 64 + (l & 15)) * 32 + xs;
  const int rb = (wc * 64 + (l & 15)) * 32 + xs;

  f32x4 acc1[4][4], acc2[4][4];
#pragma unroll
  for (int m = 0; m < 4; ++m)
#pragma unroll
    for (int n = 0; n < 4; ++n) {
      acc1[m][n] = (f32x4){0.f, 0.f, 0.f, 0.f};
      acc2[m][n] = (f32x4){0.f, 0.f, 0.f, 0.f};
    }

  auto STAGE = [&](int buf, int k0) {
    gld_lds16(sa0 + k0, &smem[buf][0][o0]);
    gld_lds16(sa1 + k0, &smem[buf][0][o1]);
    gld_lds16(sb10 + k0, &smem[buf][1][o0]);
    gld_lds16(sb11 + k0, &smem[buf][1][o1]);
    gld_lds16(sb20 + k0, &smem[buf][2][o0]);
    gld_lds16(sb21 + k0, &smem[buf][2][o1]);
  };

  STAGE(0, 0);
  __syncthreads();
  int cur = 0;
  for (int kt = 0; kt < DIM / 32; ++kt) {
    if (kt < DIM / 32 - 1) STAGE(cur ^ 1, (kt + 1) * 32);
    const u16* A = &smem[cur][0][0];
    const u16* B1 = &smem[cur][1][0];
    const u16* B2 = &smem[cur][2][0];
    s16x8 af[4];
#pragma unroll
    for (int m = 0; m < 4; ++m) af[m] = *(const s16x8*)(A + ra + m * 512);
#pragma unroll
    for (int n = 0; n < 4; ++n) {
      s16x8 bf1 = *(const s16x8*)(B1 + rb + n * 512);
      s16x8 bf2 = *(const s16x8*)(B2 + rb + n * 512);
#pragma unroll
      for (int m = 0; m < 4; ++m) {
        acc1[m][n] = __builtin_amdgcn_mfma_f32_16x16x32_bf16(af[m], bf1, acc1[m][n], 0, 0, 0);
        acc2[m][n] = __builtin_amdgcn_mfma_f32_16x16x32_bf16(af[m], bf2, acc2[m][n], 0, 0, 0);
      }
    }
    __syncthreads();
    cur ^= 1;
  }

#pragma unroll
  for (int n = 0; n < 4; ++n) {
    const int col = nt * 128 + wc * 64 + n * 16 + (l & 15);
    const float bb1 = b1[(size_t)e * HID + col];
    const float bb2 = b2[(size_t)e * HID + col];
#pragma unroll
    for (int m = 0; m < 4; ++m) {
#pragma unroll
      for (int r = 0; r < 4; ++r) {
        const int row = mt * 128 + wr * 64 + m * 16 + (l >> 4) * 4 + r;
        if (row < cnt) {
          float h = acc1[m][n][r] + bb1;
          float g = acc2[m][n][r] + bb2;
          float a = h * g / (1.f + expf(-g));
          act[(size_t)(pfx + row) * HID + col] = f2b(a);
        }
      }
    }
  }
}

// GEMM2 (split-K): out[token] += w * (act@wp^T [+ bp if sk==0]) over K-chunk sk
__global__ __launch_bounds__(256) void k_gemm2f(const u16* __restrict__ act,
    const u16* __restrict__ wpb, const float* __restrict__ bp,
    const int* __restrict__ ent, const float* __restrict__ entw,
    const int* __restrict__ counts, const int* __restrict__ prefix,
    float* __restrict__ out) {
  const int e = blockIdx.z >> 2, sk = blockIdx.z & 3;
  const int mt = blockIdx.y, nt = blockIdx.x;
  const int cnt = counts[e];
  if (mt * 128 >= cnt) return;
  const int pfx = prefix[e];
  const int tid = threadIdx.x, w = tid >> 6, l = tid & 63;

  __shared__ u16 smem[2][2][4096];

  const int r0 = tid >> 2;
  const int c = (tid & 3) ^ ((tid >> 3) & 3);
  int g0 = mt * 128 + r0;      if (g0 >= cnt) g0 = cnt - 1;
  int g1 = mt * 128 + r0 + 64; if (g1 >= cnt) g1 = cnt - 1;
  const int kbase = sk * (HID / KSPLIT);
  const u16* sa0 = act + (size_t)(pfx + g0) * HID + kbase + c * 8;
  const u16* sa1 = act + (size_t)(pfx + g1) * HID + kbase + c * 8;
  const u16* sb0 = wpb + ((size_t)e * DIM + nt * 128 + r0) * HID + kbase + c * 8;
  const u16* sb1 = sb0 + (size_t)64 * HID;
  const int o0 = tid * 8, o1 = 2048 + tid * 8;

  const int wr = w >> 1, wc = w & 1;
  const int xs = ((l >> 4) ^ ((l >> 1) & 3)) * 8;
  const int ra = (wr * 64 + (l & 15)) * 32 + xs;
  const int rb = (wc * 64 + (l & 15)) * 32 + xs;

  f32x4 acc[4][4];
#pragma unroll
  for (int m = 0; m < 4; ++m)
#pragma unroll
    for (int n = 0; n < 4; ++n) acc[m][n] = (f32x4){0.f, 0.f, 0.f, 0.f};

  auto STAGE = [&](int buf, int k0) {
    gld_lds16(sa0 + k0, &smem[buf][0][o0]);
    gld_lds16(sa1 + k0, &smem[buf][0][o1]);
    gld_lds16(sb0 + k0, &smem[buf][1][o0]);
    gld_lds16(sb1 + k0, &smem[buf][1][o1]);
  };

  STAGE(0, 0);
  __syncthreads();
  int cur = 0;
  const int NIT = HID / KSPLIT / 32;
  for (int kt = 0; kt < NIT; ++kt) {
    if (kt < NIT - 1) STAGE(cur ^ 1, (kt + 1) * 32);
    const u16* A = &smem[cur][0][0];
    const u16* B = &smem[cur][1][0];
    s16x8 af[4];
#pragma unroll
    for (int m = 0; m < 4; ++m) af[m] = *(const s16x8*)(A + ra + m * 512);
#pragma unroll
    for (int n = 0; n < 4; ++n) {
      s16x8 bf = *(const s16x8*)(B + rb + n * 512);
#pragma unroll
      for (int m = 0; m < 4; ++m)
        acc[m][n] = __builtin_amdgcn_mfma_f32_16x16x32_bf16(af[m], bf, acc[m][n], 0, 0, 0);
    }
    __syncthreads();
    cur ^= 1;
  }

#pragma unroll
  for (int n = 0; n < 4; ++n) {
    const int col = nt * 128 + wc * 64 + n * 16 + (l & 15);
    const float bpv = (sk == 0) ? bp[(size_t)e * DIM + col] : 0.f;
#pragma unroll
    for (int m = 0; m < 4; ++m) {
#pragma unroll
      for (int r = 0; r < 4; ++r) {
        const int row = mt * 128 + wr * 64 + m * 16 + (l >> 4) * 4 + r;
        if (row < cnt) {
          const int idx = pfx + row;
          const int en = ent[idx];
          const float wgt = entw[idx];
          atomicAdd(&out[(size_t)(en >> 1) * DIM + col], wgt * (acc[m][n][r] + bpv));
        }
      }
    }
  }
}

extern "C" void kernel_launch(void* const* d_in, const int* in_sizes, int n_in,
                              void* d_out, int out_size, void* d_ws, size_t ws_size,
                              hipStream_t stream) {
  const float* x      = (const float*)d_in[0];
  const float* noise  = (const float*)d_in[1];
  const float* gate_w = (const float*)d_in[2];
  const float* nw     = (const float*)d_in[3];
  const float* w1     = (const float*)d_in[4];
  const float* b1     = (const float*)d_in[5];
  const float* w2     = (const float*)d_in[6];
  const float* b2     = (const float*)d_in[7];
  const float* wp     = (const float*)d_in[8];
  const float* bp     = (const float*)d_in[9];
  float* out = (float*)d_out;
  char* ws = (char*)d_ws;

  const size_t SZ_X16 = (size_t)TOK * DIM * 2;
  const size_t SZ_ACT = (size_t)TOK * 2 * HID * 2;
  const size_t SZ_W   = (size_t)NE * HID * DIM * 2;

  u16* x16 = (u16*)ws;
  u16* act = (u16*)(ws + SZ_X16);
  u16* w1b = (u16*)(ws + SZ_X16 + SZ_ACT);
  u16* w2b = (u16*)(ws + SZ_X16 + SZ_ACT + SZ_W);
  u16* wpb = (u16*)(ws + SZ_X16 + SZ_ACT + 2 * SZ_W);
  char* meta = ws + SZ_X16 + SZ_ACT + 3 * SZ_W;
  int*   tok_e   = (int*)(meta);
  float* tok_w   = (float*)(meta + 16384);
  int*   ent     = (int*)(meta + 32768);
  float* entw    = (float*)(meta + 49152);
  int*   bhist   = (int*)(meta + 65536);
  float* bgw     = (float*)(meta + 65536 + 16384);
  int*   blk_off = (int*)(meta + 65536 + 32768);
  int*   counts  = (int*)(meta + 65536 + 49152);
  int*   prefix  = (int*)(meta + 65536 + 49152 + 256);

  hipMemsetAsync(d_out, 0, (size_t)out_size * 4, stream);
  k_gate<<<TOK / 4, 256, 0, stream>>>(x, noise, gate_w, nw, tok_e, tok_w, bhist, bgw, x16);
  k_scan<<<1, 512, 0, stream>>>(bhist, bgw, blk_off, prefix, counts, out + (size_t)TOK * DIM);
  k_build<<<TOK / 256, 256, 0, stream>>>(tok_e, tok_w, prefix, blk_off, ent, entw);
  k_castw3<<<2048, 256, 0, stream>>>(w1, w2, wp, w1b, w2b, wpb);
  k_gemm1f<<<dim3(HID / 128, TOK / 128, NE), 256, 0, stream>>>(x16, w1b, w2b, b1, b2, ent, counts, prefix, act);
  k_gemm2f<<<dim3(DIM / 128, TOK / 128, NE * KSPLIT), 256, 0, stream>>>(act, wpb, bp, ent, entw, counts, prefix, out);
}

// Round 5
// 401.957 us; speedup vs baseline: 1.6751x; 1.0231x over previous
//
#include <hip/hip_runtime.h>

#define TOK 2048
#define DIM 1024
#define HID 4096
#define NE 8
#define KSPLIT 4
#define TMAX 40

typedef unsigned short u16;
typedef __attribute__((ext_vector_type(8))) short s16x8;
typedef __attribute__((ext_vector_type(4))) float f32x4;

__device__ __forceinline__ u16 f2b(float f) {
  unsigned u = __builtin_bit_cast(unsigned, f);
  unsigned r = (u + 0x7fffu + ((u >> 16) & 1u)) >> 16;
  return (u16)r;
}

__device__ __forceinline__ void gld_lds16(const void* g, void* l) {
  __builtin_amdgcn_global_load_lds((const __attribute__((address_space(1))) void*)g,
                                   (__attribute__((address_space(3))) void*)l, 16, 0, 0);
}

// ---------------- gating (blocks 0..511) + w1/w2 bf16 cast (blocks 512..1023) ----------------
__global__ __launch_bounds__(256) void k_gate(const float* __restrict__ x,
    const float* __restrict__ noise, const float* __restrict__ gw,
    const float* __restrict__ nw, const float* __restrict__ w1,
    const float* __restrict__ w2, u16* __restrict__ w1b, u16* __restrict__ w2b,
    int* __restrict__ tok_e, float* __restrict__ tok_w,
    int* __restrict__ bhist, float* __restrict__ bgw, u16* __restrict__ x16) {
  if (blockIdx.x >= TOK / 4) {
    // ---- weight cast: 512 blocks, w1 then w2 ----
    const int cb = blockIdx.x - TOK / 4;
    const float* in = (cb < 256) ? w1 : w2;
    u16* o = (cb < 256) ? w1b : w2b;
    const size_t NPT = (size_t)NE * HID * DIM;
    const size_t stride = (size_t)256 * 256 * 8;
    for (size_t i = ((size_t)(cb & 255) * 256 + threadIdx.x) * 8; i < NPT; i += stride) {
      float4 a = *(const float4*)(in + i);
      float4 b = *(const float4*)(in + i + 4);
      u16 u[8];
      u[0] = f2b(a.x); u[1] = f2b(a.y); u[2] = f2b(a.z); u[3] = f2b(a.w);
      u[4] = f2b(b.x); u[5] = f2b(b.y); u[6] = f2b(b.z); u[7] = f2b(b.w);
      *(s16x8*)(o + i) = *(const s16x8*)u;
    }
    return;
  }
  const int wid = threadIdx.x >> 6, lane = threadIdx.x & 63;
  const int t = blockIdx.x * 4 + wid;
  const float* xr = x + (size_t)t * DIM + lane * 16;
  float acc[NE];
#pragma unroll
  for (int e = 0; e < NE; ++e) acc[e] = 0.f;
  u16 xb[16];
#pragma unroll
  for (int j = 0; j < 4; ++j) {
    float4 xv = *(const float4*)(xr + j * 4);
    xb[j * 4 + 0] = f2b(xv.x); xb[j * 4 + 1] = f2b(xv.y);
    xb[j * 4 + 2] = f2b(xv.z); xb[j * 4 + 3] = f2b(xv.w);
#pragma unroll
    for (int e = 0; e < NE; ++e) {
      float4 gv = *(const float4*)(gw + e * DIM + lane * 16 + j * 4);
      acc[e] += xv.x * gv.x + xv.y * gv.y + xv.z * gv.z + xv.w * gv.w;
    }
  }
  *(s16x8*)(x16 + (size_t)t * DIM + lane * 16) = *(const s16x8*)xb;
  *(s16x8*)(x16 + (size_t)t * DIM + lane * 16 + 8) = *(const s16x8*)(xb + 8);
#pragma unroll
  for (int e = 0; e < NE; ++e) {
#pragma unroll
    for (int off = 32; off >= 1; off >>= 1) acc[e] += __shfl_xor(acc[e], off);
  }
  float m = acc[0];
#pragma unroll
  for (int e = 1; e < NE; ++e) m = fmaxf(m, acc[e]);
  float p[NE]; float s = 0.f;
#pragma unroll
  for (int e = 0; e < NE; ++e) { p[e] = expf(acc[e] - m); s += p[e]; }
  float inv = 1.f / s;
  float v[NE];
#pragma unroll
  for (int e = 0; e < NE; ++e) v[e] = acc[e] + noise[t * NE + e] * nw[e];
  float v0 = -3.4e38f, v1 = -3.4e38f; int i0 = 0, i1 = 0;
#pragma unroll
  for (int e = 0; e < NE; ++e) {
    float ve = v[e];
    if (ve > v0) { v1 = v0; i1 = i0; v0 = ve; i0 = e; }
    else if (ve > v1) { v1 = ve; i1 = e; }
  }
  float e1 = expf(v1 - v0);
  float den = 1.f + e1;
  float w0 = 1.f / den, w1v = e1 / den;

  __shared__ float pl[4][NE];
  __shared__ int el[4][2];
  if (lane == 0) {
#pragma unroll
    for (int e = 0; e < NE; ++e) pl[wid][e] = p[e] * inv;
    el[wid][0] = i0; el[wid][1] = i1;
    tok_e[t * 2] = i0; tok_e[t * 2 + 1] = i1;
    tok_w[t * 2] = w0; tok_w[t * 2 + 1] = w1v;
  }
  __syncthreads();
  if (threadIdx.x < NE) {
    const int e = threadIdx.x;
    float ps = pl[0][e] + pl[1][e] + pl[2][e] + pl[3][e];
    int h = 0;
#pragma unroll
    for (int j = 0; j < 4; ++j) {
      h += (el[j][0] == e);
      h += (el[j][1] == e);
    }
    bgw[blockIdx.x * NE + e] = ps;
    bhist[blockIdx.x * NE + e] = h;
  }
}

// ---------------- scan over 512 gate blocks: offsets, counts, prefix, tile table, lb loss ----------------
__global__ __launch_bounds__(512) void k_scan(const int* __restrict__ bhist,
    const float* __restrict__ bgw, int* __restrict__ blk_off, int* __restrict__ prefix,
    int* __restrict__ counts, int* __restrict__ tile_tab, float* __restrict__ loss_out) {
  const int i = threadIdx.x, lane = i & 63, wv = i >> 6;
  __shared__ int wsum[8];
  __shared__ float wfs[8];
  __shared__ int etot[8];
  __shared__ float fsum[8];
  for (int e = 0; e < NE; ++e) {
    int v = bhist[i * NE + e];
    int sc = v;
#pragma unroll
    for (int off = 1; off < 64; off <<= 1) {
      int u = __shfl_up(sc, off);
      if (lane >= off) sc += u;
    }
    float f = bgw[i * NE + e];
#pragma unroll
    for (int off = 32; off >= 1; off >>= 1) f += __shfl_xor(f, off);
    if (lane == 63) wsum[wv] = sc;
    if (lane == 0) wfs[wv] = f;
    __syncthreads();
    int base = 0;
    for (int w2 = 0; w2 < wv; ++w2) base += wsum[w2];
    blk_off[i * NE + e] = base + sc - v;
    if (i == 0) {
      float tf = 0.f;
      for (int w2 = 0; w2 < 8; ++w2) tf += wfs[w2];
      fsum[e] = tf;
    }
    if (i == 511) etot[e] = base + sc;
    __syncthreads();
  }
  if (i == 0) {
    int sacc = 0;
    float l = 0.f;
    int tt = 0;
#pragma unroll
    for (int e = 0; e < NE; ++e) { prefix[e] = sacc; counts[e] = etot[e]; sacc += etot[e]; }
    for (int e = 0; e < NE; ++e) {
      const int nmt = (etot[e] + 127) >> 7;
      for (int m2 = 0; m2 < nmt; ++m2) tile_tab[tt++] = (e << 16) | m2;
    }
    for (; tt < TMAX; ++tt) tile_tab[tt] = -1;
#pragma unroll
    for (int e = 0; e < NE; ++e) {
      float d = fsum[e] * (1.f / TOK) - 0.125f;
      l += d * d;
    }
    *loss_out = l * (0.01f / NE);
  }
}

// ---------------- build compacted expert lists ----------------
__global__ __launch_bounds__(256) void k_build(const int* __restrict__ tok_e,
    const float* __restrict__ tok_w, const int* __restrict__ prefix,
    const int* __restrict__ blk_off, int* __restrict__ ent, float* __restrict__ entw) {
  const int t = blockIdx.x * 256 + threadIdx.x;
  const int g = t >> 2;
  const int base = (t & 3) * 2;
  int ee[8];
#pragma unroll
  for (int j = 0; j < 8; ++j) ee[j] = tok_e[g * 8 + j];
#pragma unroll
  for (int s = 0; s < 2; ++s) {
    const int e = ee[base + s];
    int rank = 0;
#pragma unroll
    for (int j = 0; j < 8; ++j) rank += (j < base + s) && (ee[j] == e);
    const int idx = prefix[e] + blk_off[g * NE + e] + rank;
    ent[idx] = t * 2 + s;
    entw[idx] = tok_w[t * 2 + s];
  }
}

// ================= bf16-weight GEMMs =================

// GEMM1: act = (x@w1^T+b1) * silu(x@w2^T+b2); y<8 blocks cast wp->wpb (consumed by gemm2f)
__global__ __launch_bounds__(256) void k_gemm1f(const u16* __restrict__ x16,
    const u16* __restrict__ w1b, const u16* __restrict__ w2b,
    const float* __restrict__ b1, const float* __restrict__ b2,
    const int* __restrict__ ent, const int* __restrict__ counts,
    const int* __restrict__ prefix, const int* __restrict__ tile_tab,
    const float* __restrict__ wp, u16* __restrict__ wpb, u16* __restrict__ act) {
  if (blockIdx.y < 8) {
    const int cb = blockIdx.y * 32 + blockIdx.x;   // 0..255
    const size_t NPT = (size_t)NE * HID * DIM;
    const size_t stride = (size_t)256 * 256 * 8;
    for (size_t i = ((size_t)cb * 256 + threadIdx.x) * 8; i < NPT; i += stride) {
      float4 a = *(const float4*)(wp + i);
      float4 b = *(const float4*)(wp + i + 4);
      u16 u[8];
      u[0] = f2b(a.x); u[1] = f2b(a.y); u[2] = f2b(a.z); u[3] = f2b(a.w);
      u[4] = f2b(b.x); u[5] = f2b(b.y); u[6] = f2b(b.z); u[7] = f2b(b.w);
      *(s16x8*)(wpb + i) = *(const s16x8*)u;
    }
    return;
  }
  const int tt = tile_tab[blockIdx.y - 8];
  if (tt < 0) return;
  const int e = tt >> 16, mt = tt & 0xffff, nt = blockIdx.x;
  const int cnt = counts[e];
  const int pfx = prefix[e];
  const int tid = threadIdx.x, w = tid >> 6, l = tid & 63;

  __shared__ u16 smem[2][3][4096];

  const int r0 = tid >> 2;
  const int c = (tid & 3) ^ ((tid >> 3) & 3);
  int g0 = mt * 128 + r0;      if (g0 >= cnt) g0 = cnt - 1;
  int g1 = mt * 128 + r0 + 64; if (g1 >= cnt) g1 = cnt - 1;
  const u16* sa0 = x16 + (size_t)(ent[pfx + g0] >> 1) * DIM + c * 8;
  const u16* sa1 = x16 + (size_t)(ent[pfx + g1] >> 1) * DIM + c * 8;
  const u16* sb10 = w1b + ((size_t)e * HID + nt * 128 + r0) * DIM + c * 8;
  const u16* sb11 = sb10 + (size_t)64 * DIM;
  const u16* sb20 = w2b + ((size_t)e * HID + nt * 128 + r0) * DIM + c * 8;
  const u16* sb21 = sb20 + (size_t)64 * DIM;
  const int o0 = tid * 8, o1 = 2048 + tid * 8;

  const int wr = w >> 1, wc = w & 1;
  const int xs = ((l >> 4) ^ ((l >> 1) & 3)) * 8;
  const int ra = (wr * 64 + (l & 15)) * 32 + xs;
  const int rb = (wc * 64 + (l & 15)) * 32 + xs;

  f32x4 acc1[4][4], acc2[4][4];
#pragma unroll
  for (int m = 0; m < 4; ++m)
#pragma unroll
    for (int n = 0; n < 4; ++n) {
      acc1[m][n] = (f32x4){0.f, 0.f, 0.f, 0.f};
      acc2[m][n] = (f32x4){0.f, 0.f, 0.f, 0.f};
    }

  auto STAGE = [&](int buf, int k0) {
    gld_lds16(sa0 + k0, &smem[buf][0][o0]);
    gld_lds16(sa1 + k0, &smem[buf][0][o1]);
    gld_lds16(sb10 + k0, &smem[buf][1][o0]);
    gld_lds16(sb11 + k0, &smem[buf][1][o1]);
    gld_lds16(sb20 + k0, &smem[buf][2][o0]);
    gld_lds16(sb21 + k0, &smem[buf][2][o1]);
  };

  STAGE(0, 0);
  __syncthreads();
  int cur = 0;
  for (int kt = 0; kt < DIM / 32; ++kt) {
    if (kt < DIM / 32 - 1) STAGE(cur ^ 1, (kt + 1) * 32);
    const u16* A = &smem[cur][0][0];
    const u16* B1 = &smem[cur][1][0];
    const u16* B2 = &smem[cur][2][0];
    s16x8 af[4];
#pragma unroll
    for (int m = 0; m < 4; ++m) af[m] = *(const s16x8*)(A + ra + m * 512);
#pragma unroll
    for (int n = 0; n < 4; ++n) {
      s16x8 bf1 = *(const s16x8*)(B1 + rb + n * 512);
      s16x8 bf2 = *(const s16x8*)(B2 + rb + n * 512);
#pragma unroll
      for (int m = 0; m < 4; ++m) {
        acc1[m][n] = __builtin_amdgcn_mfma_f32_16x16x32_bf16(af[m], bf1, acc1[m][n], 0, 0, 0);
        acc2[m][n] = __builtin_amdgcn_mfma_f32_16x16x32_bf16(af[m], bf2, acc2[m][n], 0, 0, 0);
      }
    }
    __syncthreads();
    cur ^= 1;
  }

#pragma unroll
  for (int n = 0; n < 4; ++n) {
    const int col = nt * 128 + wc * 64 + n * 16 + (l & 15);
    const float bb1 = b1[(size_t)e * HID + col];
    const float bb2 = b2[(size_t)e * HID + col];
#pragma unroll
    for (int m = 0; m < 4; ++m) {
#pragma unroll
      for (int r = 0; r < 4; ++r) {
        const int row = mt * 128 + wr * 64 + m * 16 + (l >> 4) * 4 + r;
        if (row < cnt) {
          float h = acc1[m][n][r] + bb1;
          float g = acc2[m][n][r] + bb2;
          float a = h * g / (1.f + expf(-g));
          act[(size_t)(pfx + row) * HID + col] = f2b(a);
        }
      }
    }
  }
}

// GEMM2 (split-K): out[token] += w * (act@wp^T [+ bp if sk==0])
__global__ __launch_bounds__(256) void k_gemm2f(const u16* __restrict__ act,
    const u16* __restrict__ wpb, const float* __restrict__ bp,
    const int* __restrict__ ent, const float* __restrict__ entw,
    const int* __restrict__ counts, const int* __restrict__ prefix,
    const int* __restrict__ tile_tab, float* __restrict__ out) {
  const int tt = tile_tab[blockIdx.y];
  if (tt < 0) return;
  const int e = tt >> 16, mt = tt & 0xffff;
  const int sk = blockIdx.z, nt = blockIdx.x;
  const int cnt = counts[e];
  const int pfx = prefix[e];
  const int tid = threadIdx.x, w = tid >> 6, l = tid & 63;

  __shared__ u16 smem[2][2][4096];

  const int r0 = tid >> 2;
  const int c = (tid & 3) ^ ((tid >> 3) & 3);
  int g0 = mt * 128 + r0;      if (g0 >= cnt) g0 = cnt - 1;
  int g1 = mt * 128 + r0 + 64; if (g1 >= cnt) g1 = cnt - 1;
  const int kbase = sk * (HID / KSPLIT);
  const u16* sa0 = act + (size_t)(pfx + g0) * HID + kbase + c * 8;
  const u16* sa1 = act + (size_t)(pfx + g1) * HID + kbase + c * 8;
  const u16* sb0 = wpb + ((size_t)e * DIM + nt * 128 + r0) * HID + kbase + c * 8;
  const u16* sb1 = sb0 + (size_t)64 * HID;
  const int o0 = tid * 8, o1 = 2048 + tid * 8;

  const int wr = w >> 1, wc = w & 1;
  const int xs = ((l >> 4) ^ ((l >> 1) & 3)) * 8;
  const int ra = (wr * 64 + (l & 15)) * 32 + xs;
  const int rb = (wc * 64 + (l & 15)) * 32 + xs;

  f32x4 acc[4][4];
#pragma unroll
  for (int m = 0; m < 4; ++m)
#pragma unroll
    for (int n = 0; n < 4; ++n) acc[m][n] = (f32x4){0.f, 0.f, 0.f, 0.f};

  auto STAGE = [&](int buf, int k0) {
    gld_lds16(sa0 + k0, &smem[buf][0][o0]);
    gld_lds16(sa1 + k0, &smem[buf][0][o1]);
    gld_lds16(sb0 + k0, &smem[buf][1][o0]);
    gld_lds16(sb1 + k0, &smem[buf][1][o1]);
  };

  STAGE(0, 0);
  __syncthreads();
  int cur = 0;
  const int NIT = HID / KSPLIT / 32;
  for (int kt = 0; kt < NIT; ++kt) {
    if (kt < NIT - 1) STAGE(cur ^ 1, (kt + 1) * 32);
    const u16* A = &smem[cur][0][0];
    const u16* B = &smem[cur][1][0];
    s16x8 af[4];
#pragma unroll
    for (int m = 0; m < 4; ++m) af[m] = *(const s16x8*)(A + ra + m * 512);
#pragma unroll
    for (int n = 0; n < 4; ++n) {
      s16x8 bf = *(const s16x8*)(B + rb + n * 512);
#pragma unroll
      for (int m = 0; m < 4; ++m)
        acc[m][n] = __builtin_amdgcn_mfma_f32_16x16x32_bf16(af[m], bf, acc[m][n], 0, 0, 0);
    }
    __syncthreads();
    cur ^= 1;
  }

#pragma unroll
  for (int n = 0; n < 4; ++n) {
    const int col = nt * 128 + wc * 64 + n * 16 + (l & 15);
    const float bpv = (sk == 0) ? bp[(size_t)e * DIM + col] : 0.f;
#pragma unroll
    for (int m = 0; m < 4; ++m) {
#pragma unroll
      for (int r = 0; r < 4; ++r) {
        const int row = mt * 128 + wr * 64 + m * 16 + (l >> 4) * 4 + r;
        if (row < cnt) {
          const int idx = pfx + row;
          const int en = ent[idx];
          const float wgt = entw[idx];
          atomicAdd(&out[(size_t)(en >> 1) * DIM + col], wgt * (acc[m][n][r] + bpv));
        }
      }
    }
  }
}

extern "C" void kernel_launch(void* const* d_in, const int* in_sizes, int n_in,
                              void* d_out, int out_size, void* d_ws, size_t ws_size,
                              hipStream_t stream) {
  const float* x      = (const float*)d_in[0];
  const float* noise  = (const float*)d_in[1];
  const float* gate_w = (const float*)d_in[2];
  const float* nw     = (const float*)d_in[3];
  const float* w1     = (const float*)d_in[4];
  const float* b1     = (const float*)d_in[5];
  const float* w2     = (const float*)d_in[6];
  const float* b2     = (const float*)d_in[7];
  const float* wp     = (const float*)d_in[8];
  const float* bp     = (const float*)d_in[9];
  float* out = (float*)d_out;
  char* ws = (char*)d_ws;

  const size_t SZ_X16 = (size_t)TOK * DIM * 2;
  const size_t SZ_ACT = (size_t)TOK * 2 * HID * 2;
  const size_t SZ_W   = (size_t)NE * HID * DIM * 2;

  u16* x16 = (u16*)ws;
  u16* act = (u16*)(ws + SZ_X16);
  u16* w1b = (u16*)(ws + SZ_X16 + SZ_ACT);
  u16* w2b = (u16*)(ws + SZ_X16 + SZ_ACT + SZ_W);
  u16* wpb = (u16*)(ws + SZ_X16 + SZ_ACT + 2 * SZ_W);
  char* meta = ws + SZ_X16 + SZ_ACT + 3 * SZ_W;
  int*   tok_e    = (int*)(meta);
  float* tok_w    = (float*)(meta + 16384);
  int*   ent      = (int*)(meta + 32768);
  float* entw     = (float*)(meta + 49152);
  int*   bhist    = (int*)(meta + 65536);
  float* bgw      = (float*)(meta + 81920);
  int*   blk_off  = (int*)(meta + 98304);
  int*   counts   = (int*)(meta + 114688);
  int*   prefix   = (int*)(meta + 114688 + 64);
  int*   tile_tab = (int*)(meta + 114688 + 128);

  hipMemsetAsync(d_out, 0, (size_t)out_size * 4, stream);
  k_gate<<<TOK / 4 + 512, 256, 0, stream>>>(x, noise, gate_w, nw, w1, w2, w1b, w2b,
                                            tok_e, tok_w, bhist, bgw, x16);
  k_scan<<<1, 512, 0, stream>>>(bhist, bgw, blk_off, prefix, counts, tile_tab,
                                out + (size_t)TOK * DIM);
  k_build<<<TOK / 256, 256, 0, stream>>>(tok_e, tok_w, prefix, blk_off, ent, entw);
  k_gemm1f<<<dim3(HID / 128, TMAX + 8), 256, 0, stream>>>(x16, w1b, w2b, b1, b2, ent,
                                                          counts, prefix, tile_tab, wp, wpb, act);
  k_gemm2f<<<dim3(DIM / 128, TMAX, KSPLIT), 256, 0, stream>>>(act, wpb, bp, ent, entw,
                                                              counts, prefix, tile_tab, out);
}

// Round 6
// 384.232 us; speedup vs baseline: 1.7524x; 1.0461x over previous
//
#include <hip/hip_runtime.h>

#define TOK 2048
#define DIM 1024
#define HID 4096
#define NE 8
#define KSPLIT 4
#define TMAX 24

typedef unsigned short u16;
typedef __attribute__((ext_vector_type(8))) short s16x8;
typedef __attribute__((ext_vector_type(4))) float f32x4;

__device__ __forceinline__ u16 f2b(float f) {
  unsigned u = __builtin_bit_cast(unsigned, f);
  unsigned r = (u + 0x7fffu + ((u >> 16) & 1u)) >> 16;
  return (u16)r;
}

__device__ __forceinline__ void gld_lds16(const void* g, void* l) {
  __builtin_amdgcn_global_load_lds((const __attribute__((address_space(1))) void*)g,
                                   (__attribute__((address_space(3))) void*)l, 16, 0, 0);
}

// ---------------- gating (blocks 0..511) + w1/w2/wp bf16 cast (blocks 512..1279) ----------------
__global__ __launch_bounds__(256) void k_gate(const float* __restrict__ x,
    const float* __restrict__ noise, const float* __restrict__ gw,
    const float* __restrict__ nw, const float* __restrict__ w1,
    const float* __restrict__ w2, const float* __restrict__ wp,
    u16* __restrict__ w1b, u16* __restrict__ w2b, u16* __restrict__ wpb,
    int* __restrict__ tok_e, float* __restrict__ tok_w,
    int* __restrict__ bhist, float* __restrict__ bgw, u16* __restrict__ x16) {
  if (blockIdx.x >= TOK / 4) {
    const int cb = blockIdx.x - TOK / 4;           // 0..767
    const int tens = cb >> 8;
    const float* in = (tens == 0) ? w1 : (tens == 1) ? w2 : wp;
    u16* o = (tens == 0) ? w1b : (tens == 1) ? w2b : wpb;
    const size_t NPT = (size_t)NE * HID * DIM;
    const size_t stride = (size_t)256 * 256 * 8;
    for (size_t i = ((size_t)(cb & 255) * 256 + threadIdx.x) * 8; i < NPT; i += stride) {
      float4 a = *(const float4*)(in + i);
      float4 b = *(const float4*)(in + i + 4);
      u16 u[8];
      u[0] = f2b(a.x); u[1] = f2b(a.y); u[2] = f2b(a.z); u[3] = f2b(a.w);
      u[4] = f2b(b.x); u[5] = f2b(b.y); u[6] = f2b(b.z); u[7] = f2b(b.w);
      *(s16x8*)(o + i) = *(const s16x8*)u;
    }
    return;
  }
  const int wid = threadIdx.x >> 6, lane = threadIdx.x & 63;
  const int t = blockIdx.x * 4 + wid;
  const float* xr = x + (size_t)t * DIM + lane * 16;
  float acc[NE];
#pragma unroll
  for (int e = 0; e < NE; ++e) acc[e] = 0.f;
  u16 xb[16];
#pragma unroll
  for (int j = 0; j < 4; ++j) {
    float4 xv = *(const float4*)(xr + j * 4);
    xb[j * 4 + 0] = f2b(xv.x); xb[j * 4 + 1] = f2b(xv.y);
    xb[j * 4 + 2] = f2b(xv.z); xb[j * 4 + 3] = f2b(xv.w);
#pragma unroll
    for (int e = 0; e < NE; ++e) {
      float4 gv = *(const float4*)(gw + e * DIM + lane * 16 + j * 4);
      acc[e] += xv.x * gv.x + xv.y * gv.y + xv.z * gv.z + xv.w * gv.w;
    }
  }
  *(s16x8*)(x16 + (size_t)t * DIM + lane * 16) = *(const s16x8*)xb;
  *(s16x8*)(x16 + (size_t)t * DIM + lane * 16 + 8) = *(const s16x8*)(xb + 8);
#pragma unroll
  for (int e = 0; e < NE; ++e) {
#pragma unroll
    for (int off = 32; off >= 1; off >>= 1) acc[e] += __shfl_xor(acc[e], off);
  }
  float m = acc[0];
#pragma unroll
  for (int e = 1; e < NE; ++e) m = fmaxf(m, acc[e]);
  float p[NE]; float s = 0.f;
#pragma unroll
  for (int e = 0; e < NE; ++e) { p[e] = expf(acc[e] - m); s += p[e]; }
  float inv = 1.f / s;
  float v[NE];
#pragma unroll
  for (int e = 0; e < NE; ++e) v[e] = acc[e] + noise[t * NE + e] * nw[e];
  float v0 = -3.4e38f, v1 = -3.4e38f; int i0 = 0, i1 = 0;
#pragma unroll
  for (int e = 0; e < NE; ++e) {
    float ve = v[e];
    if (ve > v0) { v1 = v0; i1 = i0; v0 = ve; i0 = e; }
    else if (ve > v1) { v1 = ve; i1 = e; }
  }
  float e1 = expf(v1 - v0);
  float den = 1.f + e1;
  float w0 = 1.f / den, w1v = e1 / den;

  __shared__ float pl[4][NE];
  __shared__ int el[4][2];
  if (lane == 0) {
#pragma unroll
    for (int e = 0; e < NE; ++e) pl[wid][e] = p[e] * inv;
    el[wid][0] = i0; el[wid][1] = i1;
    tok_e[t * 2] = i0; tok_e[t * 2 + 1] = i1;
    tok_w[t * 2] = w0; tok_w[t * 2 + 1] = w1v;
  }
  __syncthreads();
  if (threadIdx.x < NE) {
    const int e = threadIdx.x;
    float ps = pl[0][e] + pl[1][e] + pl[2][e] + pl[3][e];
    int h = 0;
#pragma unroll
    for (int j = 0; j < 4; ++j) {
      h += (el[j][0] == e);
      h += (el[j][1] == e);
    }
    bgw[blockIdx.x * NE + e] = ps;
    bhist[blockIdx.x * NE + e] = h;
  }
}

// ---------------- scan: offsets, counts, prefix, 256-row tile table, lb loss ----------------
__global__ __launch_bounds__(512) void k_scan(const int* __restrict__ bhist,
    const float* __restrict__ bgw, int* __restrict__ blk_off, int* __restrict__ prefix,
    int* __restrict__ counts, int* __restrict__ tile_tab, float* __restrict__ loss_out) {
  const int i = threadIdx.x, lane = i & 63, wv = i >> 6;
  __shared__ int wsum[8];
  __shared__ float wfs[8];
  __shared__ int etot[8];
  __shared__ float fsum[8];
  for (int e = 0; e < NE; ++e) {
    int v = bhist[i * NE + e];
    int sc = v;
#pragma unroll
    for (int off = 1; off < 64; off <<= 1) {
      int u = __shfl_up(sc, off);
      if (lane >= off) sc += u;
    }
    float f = bgw[i * NE + e];
#pragma unroll
    for (int off = 32; off >= 1; off >>= 1) f += __shfl_xor(f, off);
    if (lane == 63) wsum[wv] = sc;
    if (lane == 0) wfs[wv] = f;
    __syncthreads();
    int base = 0;
    for (int w2 = 0; w2 < wv; ++w2) base += wsum[w2];
    blk_off[i * NE + e] = base + sc - v;
    if (i == 0) {
      float tf = 0.f;
      for (int w2 = 0; w2 < 8; ++w2) tf += wfs[w2];
      fsum[e] = tf;
    }
    if (i == 511) etot[e] = base + sc;
    __syncthreads();
  }
  if (i == 0) {
    int sacc = 0;
    float l = 0.f;
    int tt = 0;
#pragma unroll
    for (int e = 0; e < NE; ++e) { prefix[e] = sacc; counts[e] = etot[e]; sacc += etot[e]; }
    for (int e = 0; e < NE; ++e) {
      const int nmt = (etot[e] + 255) >> 8;
      for (int m2 = 0; m2 < nmt; ++m2) tile_tab[tt++] = (e << 16) | m2;
    }
    for (; tt < TMAX; ++tt) tile_tab[tt] = -1;
#pragma unroll
    for (int e = 0; e < NE; ++e) {
      float d = fsum[e] * (1.f / TOK) - 0.125f;
      l += d * d;
    }
    *loss_out = l * (0.01f / NE);
  }
}

// ---------------- build compacted expert lists + inverse map ----------------
__global__ __launch_bounds__(256) void k_build(const int* __restrict__ tok_e,
    const float* __restrict__ tok_w, const int* __restrict__ prefix,
    const int* __restrict__ blk_off, int* __restrict__ ent, float* __restrict__ entw,
    int* __restrict__ inv) {
  const int t = blockIdx.x * 256 + threadIdx.x;
  const int g = t >> 2;
  const int base = (t & 3) * 2;
  int ee[8];
#pragma unroll
  for (int j = 0; j < 8; ++j) ee[j] = tok_e[g * 8 + j];
#pragma unroll
  for (int s = 0; s < 2; ++s) {
    const int e = ee[base + s];
    int rank = 0;
#pragma unroll
    for (int j = 0; j < 8; ++j) rank += (j < base + s) && (ee[j] == e);
    const int idx = prefix[e] + blk_off[g * NE + e] + rank;
    ent[idx] = t * 2 + s;
    entw[idx] = tok_w[t * 2 + s];
    inv[t * 2 + s] = idx;
  }
}

// ================= GEMM1: 256x128 tile, 8 waves. act = (x@w1^T+b1)*silu(x@w2^T+b2) =================
__global__ __launch_bounds__(512) void k_gemm1f(const u16* __restrict__ x16,
    const u16* __restrict__ w1b, const u16* __restrict__ w2b,
    const float* __restrict__ b1, const float* __restrict__ b2,
    const int* __restrict__ ent, const int* __restrict__ counts,
    const int* __restrict__ prefix, const int* __restrict__ tile_tab,
    u16* __restrict__ act) {
  const int tt = tile_tab[blockIdx.y];
  if (tt < 0) return;
  const int e = tt >> 16, mt = tt & 0xffff, nt = blockIdx.x;
  const int cnt = counts[e];
  const int pfx = prefix[e];
  const int tid = threadIdx.x, w = tid >> 6, l = tid & 63;

  __shared__ u16 smem[2][16384];   // A: [0,8192) 256x32, B1: [8192,12288), B2: [12288,16384)

  const int r0 = tid >> 2;                       // 0..127
  const int c = (tid & 3) ^ ((tid >> 3) & 3);
  int g0 = mt * 256 + r0;       if (g0 >= cnt) g0 = cnt - 1;
  int g1 = mt * 256 + 128 + r0; if (g1 >= cnt) g1 = cnt - 1;
  const u16* sa0 = x16 + (size_t)(ent[pfx + g0] >> 1) * DIM + c * 8;
  const u16* sa1 = x16 + (size_t)(ent[pfx + g1] >> 1) * DIM + c * 8;
  const u16* sb1 = w1b + ((size_t)e * HID + nt * 128 + r0) * DIM + c * 8;
  const u16* sb2 = w2b + ((size_t)e * HID + nt * 128 + r0) * DIM + c * 8;
  const int oA0 = tid * 8, oA1 = 4096 + tid * 8;
  const int oB1 = 8192 + tid * 8, oB2 = 12288 + tid * 8;

  const int wr = w >> 1, wc = w & 1;             // 4 x 2 wave grid
  const int xs = ((l >> 4) ^ ((l >> 1) & 3)) * 8;
  const int ra = (wr * 64 + (l & 15)) * 32 + xs;
  const int rb = (wc * 64 + (l & 15)) * 32 + xs;

  f32x4 acc1[4][4], acc2[4][4];
#pragma unroll
  for (int m = 0; m < 4; ++m)
#pragma unroll
    for (int n = 0; n < 4; ++n) {
      acc1[m][n] = (f32x4){0.f, 0.f, 0.f, 0.f};
      acc2[m][n] = (f32x4){0.f, 0.f, 0.f, 0.f};
    }

  auto STAGE = [&](int buf, int k0) {
    gld_lds16(sa0 + k0, &smem[buf][oA0]);
    gld_lds16(sa1 + k0, &smem[buf][oA1]);
    gld_lds16(sb1 + k0, &smem[buf][oB1]);
    gld_lds16(sb2 + k0, &smem[buf][oB2]);
  };

  STAGE(0, 0);
  __syncthreads();
  int cur = 0;
  for (int kt = 0; kt < DIM / 32; ++kt) {
    if (kt < DIM / 32 - 1) STAGE(cur ^ 1, (kt + 1) * 32);
    const u16* S = &smem[cur][0];
    s16x8 af[4];
#pragma unroll
    for (int m = 0; m < 4; ++m) af[m] = *(const s16x8*)(S + ra + m * 512);
#pragma unroll
    for (int n = 0; n < 4; ++n) {
      s16x8 bf1 = *(const s16x8*)(S + 8192 + rb + n * 512);
      s16x8 bf2 = *(const s16x8*)(S + 12288 + rb + n * 512);
#pragma unroll
      for (int m = 0; m < 4; ++m) {
        acc1[m][n] = __builtin_amdgcn_mfma_f32_16x16x32_bf16(af[m], bf1, acc1[m][n], 0, 0, 0);
        acc2[m][n] = __builtin_amdgcn_mfma_f32_16x16x32_bf16(af[m], bf2, acc2[m][n], 0, 0, 0);
      }
    }
    __syncthreads();
    cur ^= 1;
  }

#pragma unroll
  for (int n = 0; n < 4; ++n) {
    const int col = nt * 128 + wc * 64 + n * 16 + (l & 15);
    const float bb1 = b1[(size_t)e * HID + col];
    const float bb2 = b2[(size_t)e * HID + col];
#pragma unroll
    for (int m = 0; m < 4; ++m) {
#pragma unroll
      for (int r = 0; r < 4; ++r) {
        const int row = mt * 256 + wr * 64 + m * 16 + (l >> 4) * 4 + r;
        if (row < cnt) {
          float h = acc1[m][n][r] + bb1;
          float g = acc2[m][n][r] + bb2;
          float a = h * g / (1.f + expf(-g));
          act[(size_t)(pfx + row) * HID + col] = f2b(a);
        }
      }
    }
  }
}

// ================= GEMM2: 256x256 tile, 8 waves, split-K=4, plain stores =================
__global__ __launch_bounds__(512) void k_gemm2f(const u16* __restrict__ act,
    const u16* __restrict__ wpb, const float* __restrict__ bp,
    const float* __restrict__ entw, const int* __restrict__ counts,
    const int* __restrict__ prefix, const int* __restrict__ tile_tab,
    float* __restrict__ yp) {
  const int tt = tile_tab[blockIdx.y];
  if (tt < 0) return;
  const int e = tt >> 16, mt = tt & 0xffff;
  const int sk = blockIdx.z, nt = blockIdx.x;   // nt 0..3
  const int cnt = counts[e];
  const int pfx = prefix[e];
  const int tid = threadIdx.x, w = tid >> 6, l = tid & 63;

  __shared__ u16 smem[2][16384];   // A: [0,8192) 256x32, B: [8192,16384) 256x32

  const int r0 = tid >> 2;
  const int c = (tid & 3) ^ ((tid >> 3) & 3);
  int g0 = mt * 256 + r0;       if (g0 >= cnt) g0 = cnt - 1;
  int g1 = mt * 256 + 128 + r0; if (g1 >= cnt) g1 = cnt - 1;
  const int kbase = sk * (HID / KSPLIT);
  const u16* sa0 = act + (size_t)(pfx + g0) * HID + kbase + c * 8;
  const u16* sa1 = act + (size_t)(pfx + g1) * HID + kbase + c * 8;
  const u16* sb0 = wpb + ((size_t)e * DIM + nt * 256 + r0) * HID + kbase + c * 8;
  const u16* sb1 = sb0 + (size_t)128 * HID;
  const int oA0 = tid * 8, oA1 = 4096 + tid * 8;
  const int oB0 = 8192 + tid * 8, oB1 = 12288 + tid * 8;

  const int wr = w >> 2, wc = w & 3;             // 2 x 4 wave grid: 128 rows x 64 cols each
  const int xs = ((l >> 4) ^ ((l >> 1) & 3)) * 8;
  const int ra = (wr * 128 + (l & 15)) * 32 + xs;
  const int rb = 8192 + (wc * 64 + (l & 15)) * 32 + xs;

  f32x4 acc[8][4];
#pragma unroll
  for (int m = 0; m < 8; ++m)
#pragma unroll
    for (int n = 0; n < 4; ++n) acc[m][n] = (f32x4){0.f, 0.f, 0.f, 0.f};

  auto STAGE = [&](int buf, int k0) {
    gld_lds16(sa0 + k0, &smem[buf][oA0]);
    gld_lds16(sa1 + k0, &smem[buf][oA1]);
    gld_lds16(sb0 + k0, &smem[buf][oB0]);
    gld_lds16(sb1 + k0, &smem[buf][oB1]);
  };

  STAGE(0, 0);
  __syncthreads();
  int cur = 0;
  const int NIT = HID / KSPLIT / 32;
  for (int kt = 0; kt < NIT; ++kt) {
    if (kt < NIT - 1) STAGE(cur ^ 1, (kt + 1) * 32);
    const u16* S = &smem[cur][0];
#pragma unroll
    for (int n = 0; n < 4; ++n) {
      s16x8 bf = *(const s16x8*)(S + rb + n * 512);
#pragma unroll
      for (int m = 0; m < 8; ++m) {
        s16x8 af = *(const s16x8*)(S + ra + m * 512);
        acc[m][n] = __builtin_amdgcn_mfma_f32_16x16x32_bf16(af, bf, acc[m][n], 0, 0, 0);
      }
    }
    __syncthreads();
    cur ^= 1;
  }

#pragma unroll
  for (int n = 0; n < 4; ++n) {
    const int col = nt * 256 + wc * 64 + n * 16 + (l & 15);
    const float bpv = (sk == 0) ? bp[(size_t)e * DIM + col] : 0.f;
#pragma unroll
    for (int m = 0; m < 8; ++m) {
#pragma unroll
      for (int r = 0; r < 4; ++r) {
        const int row = mt * 256 + wr * 128 + m * 16 + (l >> 4) * 4 + r;
        if (row < cnt) {
          const int idx = pfx + row;
          yp[((size_t)sk * (TOK * 2) + idx) * DIM + col] = entw[idx] * (acc[m][n][r] + bpv);
        }
      }
    }
  }
}

// ---------------- final: out[t] = sum over 2 slots x KSPLIT partials ----------------
__global__ __launch_bounds__(256) void k_final(const float* __restrict__ yp,
    const int* __restrict__ inv, float* __restrict__ out) {
  const int t = blockIdx.x;
  const int d = threadIdx.x * 4;
  const int i0 = inv[t * 2], i1 = inv[t * 2 + 1];
  float4 s = {0.f, 0.f, 0.f, 0.f};
#pragma unroll
  for (int sk = 0; sk < KSPLIT; ++sk) {
    float4 a = *(const float4*)(yp + ((size_t)sk * (TOK * 2) + i0) * DIM + d);
    float4 b = *(const float4*)(yp + ((size_t)sk * (TOK * 2) + i1) * DIM + d);
    s.x += a.x + b.x; s.y += a.y + b.y; s.z += a.z + b.z; s.w += a.w + b.w;
  }
  *(float4*)(out + (size_t)t * DIM + d) = s;
}

extern "C" void kernel_launch(void* const* d_in, const int* in_sizes, int n_in,
                              void* d_out, int out_size, void* d_ws, size_t ws_size,
                              hipStream_t stream) {
  const float* x      = (const float*)d_in[0];
  const float* noise  = (const float*)d_in[1];
  const float* gate_w = (const float*)d_in[2];
  const float* nw     = (const float*)d_in[3];
  const float* w1     = (const float*)d_in[4];
  const float* b1     = (const float*)d_in[5];
  const float* w2     = (const float*)d_in[6];
  const float* b2     = (const float*)d_in[7];
  const float* wp     = (const float*)d_in[8];
  const float* bp     = (const float*)d_in[9];
  float* out = (float*)d_out;
  char* ws = (char*)d_ws;

  const size_t SZ_X16 = (size_t)TOK * DIM * 2;          //  4.2 MB
  const size_t SZ_ACT = (size_t)TOK * 2 * HID * 2;      // 33.6 MB
  const size_t SZ_W   = (size_t)NE * HID * DIM * 2;     // 67.1 MB each

  u16* x16 = (u16*)ws;
  u16* act = (u16*)(ws + SZ_X16);
  u16* w1b = (u16*)(ws + SZ_X16 + SZ_ACT);
  u16* w2b = (u16*)(ws + SZ_X16 + SZ_ACT + SZ_W);
  u16* wpb = (u16*)(ws + SZ_X16 + SZ_ACT + 2 * SZ_W);
  // yp (KSPLIT x 4096 x 1024 fp32 = 67.1 MB) overlays w1b: w1b is dead once gemm1 finishes.
  float* yp = (float*)w1b;
  char* meta = ws + SZ_X16 + SZ_ACT + 3 * SZ_W;
  int*   tok_e    = (int*)(meta);
  float* tok_w    = (float*)(meta + 16384);
  int*   ent      = (int*)(meta + 32768);
  float* entw     = (float*)(meta + 49152);
  int*   bhist    = (int*)(meta + 65536);
  float* bgw      = (float*)(meta + 81920);
  int*   blk_off  = (int*)(meta + 98304);
  int*   inv      = (int*)(meta + 114688);
  int*   counts   = (int*)(meta + 131072);
  int*   prefix   = (int*)(meta + 131072 + 64);
  int*   tile_tab = (int*)(meta + 131072 + 128);

  k_gate<<<TOK / 4 + 768, 256, 0, stream>>>(x, noise, gate_w, nw, w1, w2, wp,
                                            w1b, w2b, wpb, tok_e, tok_w, bhist, bgw, x16);
  k_scan<<<1, 512, 0, stream>>>(bhist, bgw, blk_off, prefix, counts, tile_tab,
                                out + (size_t)TOK * DIM);
  k_build<<<TOK / 256, 256, 0, stream>>>(tok_e, tok_w, prefix, blk_off, ent, entw, inv);
  k_gemm1f<<<dim3(HID / 128, TMAX), 512, 0, stream>>>(x16, w1b, w2b, b1, b2, ent,
                                                      counts, prefix, tile_tab, act);
  k_gemm2f<<<dim3(DIM / 256, TMAX, KSPLIT), 512, 0, stream>>>(act, wpb, bp, entw,
                                                              counts, prefix, tile_tab, yp);
  k_final<<<TOK, 256, 0, stream>>>(yp, inv, out);
}